// Round 1
// baseline (1558.241 us; speedup 1.0000x reference)
//
#include <hip/hip_runtime.h>
#include <hip/hip_bf16.h>

typedef unsigned short u16;
typedef unsigned int   u32;
typedef __attribute__((ext_vector_type(8))) short bf16x8;
typedef __attribute__((ext_vector_type(4))) float f32x4;
typedef __attribute__((ext_vector_type(4))) u16   u16x4;

constexpr int TT  = 2;
constexpr int NN  = 16384;
constexpr int EE  = 262144;

__device__ __forceinline__ u16 f2b(float f){
  u32 x = __float_as_uint(f);
  u32 r = (x + 0x7fffu + ((x >> 16) & 1u)) >> 16;
  return (u16)r;
}
__device__ __forceinline__ float b2f(u16 u){ return __uint_as_float(((u32)u) << 16); }
__device__ __forceinline__ float gelu_f(float x){ return 0.5f * x * (1.f + erff(x * 0.70710678118654752f)); }

// ---------------- CSR build ----------------
__global__ void csr_hist(const int* __restrict__ dst, int* __restrict__ cnt){
  int id = blockIdx.x*256 + threadIdx.x;           // < 2E
  int e = id >> 18;
  atomicAdd(&cnt[e*NN + dst[id]], 1);
}

__global__ void csr_scan(const int* __restrict__ cnt, int* __restrict__ offs){
  const int e = blockIdx.x, tid = threadIdx.x;     // 2 blocks x 256
  const int CH = NN/256;                           // 64
  const int* c = cnt + e*NN;
  int* of = offs + e*(NN+1);
  const int base = tid*CH;
  int s = 0;
  for(int i=0;i<CH;i++) s += c[base+i];
  __shared__ int sm[256];
  sm[tid] = s; __syncthreads();
  for(int o=1;o<256;o<<=1){
    int v = (tid>=o) ? sm[tid-o] : 0;
    __syncthreads();
    sm[tid] += v;
    __syncthreads();
  }
  int run = sm[tid] - s;                           // exclusive prefix of chunk
  for(int i=0;i<CH;i++){ of[base+i] = run; run += c[base+i]; }
  if(tid==255) of[NN] = run;
}

__global__ void csr_scatter(const int* __restrict__ dst, const int* __restrict__ src,
                            const int* __restrict__ offs, int* __restrict__ cur,
                            int* __restrict__ elist){
  int id = blockIdx.x*256 + threadIdx.x;
  int e = id >> 18;
  int d = dst[id];
  int pos = offs[e*(NN+1)+d] + atomicAdd(&cur[e*NN+d], 1);
  elist[e*EE + pos] = src[id];                     // store SOURCE id directly
}

// ---------------- transpose + bf16 convert (weights) ----------------
// in: (K x Nc) fp32 row-major, out: (Nc x K) bf16 row-major; z batches matrices
__global__ void tconv(const float* __restrict__ in, u16* __restrict__ out, int K, int Nc){
  __shared__ float tile[32][33];
  const long base = (long)blockIdx.z * K * Nc;
  const int k0 = blockIdx.x*32, n0 = blockIdx.y*32;
  const int tx = threadIdx.x, ty = threadIdx.y;    // 32 x 8
  for(int i=0;i<32;i+=8)
    tile[ty+i][tx] = in[base + (long)(k0+ty+i)*Nc + n0+tx];
  __syncthreads();
  for(int i=0;i<32;i+=8)
    out[base + (long)(n0+ty+i)*K + k0+tx] = f2b(tile[tx][ty+i]);
}

// ---------------- generic bf16-MFMA GEMM ----------------
// C = epi(A @ B^T_stored + bias).  Bt is (Nc x K) bf16 (pre-transposed).
// EPI: 0 = fp32 +bias; 1 = gelu->bf16; 2 = tanh->bf16; 3 = residual mix fp32
// ASRC: 0 = fp32 A; 1 = bf16 A
template<int BM,int BN,int BK,int WM,int WN,int ASRC,int EPI>
__global__ void __launch_bounds__(256,2)
gemm_k(const void* __restrict__ Av, const u16* __restrict__ Bt,
       const float* __restrict__ bias, void* __restrict__ Cv,
       int K, int lda, int ldc,
       long strideA, long strideB, long strideBias, long strideC,
       const float* __restrict__ resid, const float* __restrict__ resgate,
       const int* __restrict__ selp)
{
  constexpr int WTM = BM/WM, WTN = BN/WN;
  constexpr int RM = WTM/16, RN = WTN/16;
  constexpr int LA = BK + 8, LB = BK + 8;          // pad: 2-way LDS aliasing only
  __shared__ u16 lA[BM*LA];
  __shared__ u16 lB[BN*LB];

  const int tid = threadIdx.x;
  const int by  = blockIdx.y;
  const int m0  = blockIdx.x * BM;
  const int lane = tid & 63, wvi = tid >> 6;
  const int wr = wvi / WN, wc = wvi % WN;
  const int wr0 = wr * WTM, wc0 = wc * WTN;
  const int l16 = lane & 15, qd = lane >> 4;

  long aoff = (long)by * strideA;
  if (selp) aoff += (long)selp[0] * strideA;
  const float* A32 = (const float*)Av;
  const u16*   A16 = (const u16*)Av;
  const u16*   Bp  = Bt + (long)by * strideB;

  f32x4 acc[RM][RN];
  #pragma unroll
  for(int i=0;i<RM;i++)
    #pragma unroll
    for(int j=0;j<RN;j++) acc[i][j] = (f32x4){0.f,0.f,0.f,0.f};

  for(int k0=0;k0<K;k0+=BK){
    if constexpr (ASRC == 0){
      for(int idx=tid; idx < BM*BK/4; idx += 256){
        int r = idx / (BK/4), c = (idx % (BK/4))*4;
        const float4 v = *(const float4*)(A32 + aoff + (long)(m0+r)*lda + k0 + c);
        u16x4 ov; ov.x=f2b(v.x); ov.y=f2b(v.y); ov.z=f2b(v.z); ov.w=f2b(v.w);
        *(u16x4*)&lA[r*LA + c] = ov;
      }
    } else {
      for(int idx=tid; idx < BM*BK/8; idx += 256){
        int r = idx / (BK/8), c = (idx % (BK/8))*8;
        *(uint4*)&lA[r*LA + c] = *(const uint4*)(A16 + aoff + (long)(m0+r)*lda + k0 + c);
      }
    }
    for(int idx=tid; idx < BN*BK/8; idx += 256){
      int n = idx / (BK/8), c = (idx % (BK/8))*8;
      *(uint4*)&lB[n*LB + c] = *(const uint4*)(Bp + (long)n*K + k0 + c);
    }
    __syncthreads();
    #pragma unroll
    for(int ks=0; ks<BK; ks+=32){
      bf16x8 af[RM], bfr[RN];
      #pragma unroll
      for(int i=0;i<RM;i++) af[i]  = *(const bf16x8*)&lA[(wr0 + i*16 + l16)*LA + ks + qd*8];
      #pragma unroll
      for(int j=0;j<RN;j++) bfr[j] = *(const bf16x8*)&lB[(wc0 + j*16 + l16)*LB + ks + qd*8];
      #pragma unroll
      for(int i=0;i<RM;i++)
        #pragma unroll
        for(int j=0;j<RN;j++)
          acc[i][j] = __builtin_amdgcn_mfma_f32_16x16x32_bf16(af[i], bfr[j], acc[i][j], 0,0,0);
    }
    __syncthreads();
  }

  float alpha = 0.f;
  if constexpr (EPI == 3) alpha = 1.f/(1.f + expf(-resgate[by]));
  #pragma unroll
  for(int i=0;i<RM;i++){
    #pragma unroll
    for(int j=0;j<RN;j++){
      const int col = wc0 + j*16 + l16;
      const float bv = bias[(long)by*strideBias + col];
      #pragma unroll
      for(int r=0;r<4;r++){
        const int row = m0 + wr0 + i*16 + qd*4 + r;
        float v = acc[i][j][r] + bv;
        const long cidx = (long)by*strideC + (long)row*ldc + col;
        if constexpr (EPI == 0) ((float*)Cv)[cidx] = v;
        else if constexpr (EPI == 1) ((u16*)Cv)[cidx] = f2b(gelu_f(v));
        else if constexpr (EPI == 2) ((u16*)Cv)[cidx] = f2b(tanhf(v));
        else {
          const float hv = resid[(long)by*strideC + (long)row*ldc + col];
          ((float*)Cv)[cidx] = v*alpha + hv*(1.f - alpha);
        }
      }
    }
  }
}

// ---------------- posvect: A generated from per-row scalar, fused GEMM ----------------
__global__ void __launch_bounds__(256,2)
posvect_k(const float* __restrict__ scalars,
          const float* __restrict__ ww, const float* __restrict__ wb,
          const float* __restrict__ lw, const float* __restrict__ lb,
          const float* __restrict__ sw, const float* __restrict__ sb,
          const float* __restrict__ gw, const float* __restrict__ gb,
          const u16* __restrict__ fwt, const float* __restrict__ fcb,
          u16* __restrict__ zb)
{
  __shared__ u16 lA[64*72];
  __shared__ u16 lB[256*72];
  __shared__ float xs[64];
  const int tid = threadIdx.x;
  const int by = blockIdx.y;
  const int t = by / 6, m = by % 6;
  const int m0 = blockIdx.x * 64;
  const int lane = tid & 63, wvi = tid >> 6;
  const int wc0 = wvi * 64;
  const int l16 = lane & 15, qd = lane >> 4;
  const int jl = tid & 63, rb0 = (tid >> 6) * 16;
  const int pofs = (t*6 + m) * 256;

  if (tid < 64) xs[tid] = scalars[((long)t*NN + m0 + tid)*6 + m];

  const u16* Bp = fwt + (long)by * (1024*256);

  f32x4 acc[4][4];
  #pragma unroll
  for(int i=0;i<4;i++)
    #pragma unroll
    for(int j=0;j<4;j++) acc[i][j] = (f32x4){0.f,0.f,0.f,0.f};

  __syncthreads();

  for(int k0=0;k0<1024;k0+=64){
    const int j  = k0 + jl;
    const int hh = j & 255;
    const int ia = j >> 8;                         // uniform over the block
    float wvv, bvv;
    if      (ia==0){ wvv=ww[pofs+hh]; bvv=wb[pofs+hh]; }
    else if (ia==1){ wvv=lw[pofs+hh]; bvv=lb[pofs+hh]; }
    else if (ia==2){ wvv=sw[pofs+hh]; bvv=sb[pofs+hh]; }
    else           { wvv=gw[pofs+hh]; bvv=gb[pofs+hh]; }
    #pragma unroll
    for(int r=0;r<16;r++){
      const int rr = rb0 + r;
      const float y = xs[rr]*wvv + bvv;
      float a;
      if      (ia==0) a = sinf(y);
      else if (ia==1) a = y;
      else if (ia==2) a = (y>0.f) ? (y + log1pf(expf(-y))) : log1pf(expf(y));
      else            a = 1.f/(1.f+expf(-y));
      lA[rr*72 + jl] = f2b(a);
    }
    for(int idx=tid; idx<2048; idx+=256){
      int n = idx >> 3, c = (idx & 7)*8;
      *(uint4*)&lB[n*72 + c] = *(const uint4*)(Bp + (long)n*1024 + k0 + c);
    }
    __syncthreads();
    #pragma unroll
    for(int ks=0; ks<64; ks+=32){
      bf16x8 af[4], bfr[4];
      #pragma unroll
      for(int i=0;i<4;i++) af[i]  = *(const bf16x8*)&lA[(i*16 + l16)*72 + ks + qd*8];
      #pragma unroll
      for(int jj=0;jj<4;jj++) bfr[jj] = *(const bf16x8*)&lB[(wc0 + jj*16 + l16)*72 + ks + qd*8];
      #pragma unroll
      for(int i=0;i<4;i++)
        #pragma unroll
        for(int jj=0;jj<4;jj++)
          acc[i][jj] = __builtin_amdgcn_mfma_f32_16x16x32_bf16(af[i], bfr[jj], acc[i][jj], 0,0,0);
    }
    __syncthreads();
  }

  #pragma unroll
  for(int i=0;i<4;i++){
    #pragma unroll
    for(int jj=0;jj<4;jj++){
      const int col = wc0 + jj*16 + l16;
      const float bv = fcb[pofs + col];
      #pragma unroll
      for(int r=0;r<4;r++){
        const int row = m0 + i*16 + qd*4 + r;
        const float v = acc[i][jj][r] + bv;
        zb[((long)t*NN + row)*1792 + (m+1)*256 + col] = f2b(gelu_f(v));
      }
    }
  }
}

// ---------------- IMA: dot with ima_w2, then softmax-combine ----------------
__global__ void ima_dot(const u16* __restrict__ W1, const float* __restrict__ w2,
                        float* __restrict__ wbuf){
  const int row = blockIdx.x*4 + (threadIdx.x>>6);
  const int lane = threadIdx.x & 63;
  const u32 u = *(const u32*)&W1[(long)row*128 + lane*2];
  const float2 wv = *(const float2*)&w2[lane*2];
  float s = b2f((u16)(u & 0xffffu))*wv.x + b2f((u16)(u >> 16))*wv.y;
  #pragma unroll
  for(int o=1;o<64;o<<=1) s += __shfl_xor(s,o);
  if (lane == 0) wbuf[row] = s;
}

__global__ void ima_combine(const u16* __restrict__ zb, const float* __restrict__ wbuf,
                            float* __restrict__ H){
  const int row = blockIdx.x*4 + (threadIdx.x>>6);   // (t*N+n)
  const int lane = threadIdx.x & 63;
  const float* w7 = wbuf + (long)row*7;
  float w[7]; float mx = -1e30f;
  #pragma unroll
  for(int m=0;m<7;m++){ w[m] = w7[m]; mx = fmaxf(mx, w[m]); }
  float sum = 0.f;
  #pragma unroll
  for(int m=0;m<7;m++){ w[m] = expf(w[m]-mx); sum += w[m]; }
  const float inv = 1.f/sum;
  float4 acc = {0,0,0,0};
  #pragma unroll
  for(int m=0;m<7;m++){
    const u16x4 z4 = *(const u16x4*)&zb[((long)row*7 + m)*256 + lane*4];
    const float p = w[m]*inv;
    acc.x += p*b2f(z4.x); acc.y += p*b2f(z4.y); acc.z += p*b2f(z4.z); acc.w += p*b2f(z4.w);
  }
  *(float4*)&H[(long)row*256 + lane*4] = acc;
}

// ---------------- per-head 32x32 transform, in place ----------------
// buf (T,N,256); W = wall[(l*2 + t)*8 + h] (32x32): out_j = sum_i x_i W[i][j]
__global__ void head_transform(float* __restrict__ buf, const float* __restrict__ wall, int l){
  const int th = blockIdx.y;
  const int t = th >> 3, h = th & 7;
  const int n0 = blockIdx.x*32;
  __shared__ float Ws[32][33];
  __shared__ float Xs[32][33];
  const float* W = wall + (((long)(l*2 + t)*8 + h)*1024);
  for(int idx=threadIdx.x; idx<1024; idx+=256) Ws[idx>>5][idx&31] = W[idx];
  for(int idx=threadIdx.x; idx<1024; idx+=256){
    int r = idx>>5, c = idx&31;
    Xs[r][c] = buf[((long)t*NN + n0 + r)*256 + h*32 + c];
  }
  __syncthreads();
  const int r = threadIdx.x>>3, j0 = (threadIdx.x&7)*4;
  float o0=0.f,o1=0.f,o2=0.f,o3=0.f;
  #pragma unroll
  for(int i=0;i<32;i++){
    const float x = Xs[r][i];
    o0 += x*Ws[i][j0]; o1 += x*Ws[i][j0+1]; o2 += x*Ws[i][j0+2]; o3 += x*Ws[i][j0+3];
  }
  float4 ov = {o0,o1,o2,o3};
  *(float4*)&buf[((long)t*NN + n0 + r)*256 + h*32 + j0] = ov;
}

// ---------------- attention aggregation: one wave per destination node ----------------
__global__ void attn_agg(const float* __restrict__ Q, const float* __restrict__ KE,
                         const float* __restrict__ VE, float* __restrict__ AGG,
                         const int* __restrict__ offs, const int* __restrict__ elist,
                         const float* __restrict__ canon, int e, int dt){
  const int d = blockIdx.x*4 + (threadIdx.x>>6);
  const int lane = threadIdx.x & 63;
  const float scale = canon[lane>>3] * 0.17677669529663687f;  // canon[h]/sqrt(32)
  const float4 q4 = *(const float4*)&Q[((long)dt*NN + d)*256 + lane*4];
  const int p0 = offs[e*(NN+1) + d], p1 = offs[e*(NN+1) + d + 1];
  const int* el = elist + (long)e*EE;
  const float* KEb = KE + (long)e*NN*256;
  const float* VEb = VE + (long)e*NN*256;
  float4 acc = {0,0,0,0}; float den = 0.f;
  for(int p=p0;p<p1;++p){
    const int s = el[p];
    const float4 k4 = *(const float4*)&KEb[(long)s*256 + lane*4];
    const float4 v4 = *(const float4*)&VEb[(long)s*256 + lane*4];
    float dp = q4.x*k4.x + q4.y*k4.y + q4.z*k4.z + q4.w*k4.w;
    dp += __shfl_xor(dp,1); dp += __shfl_xor(dp,2); dp += __shfl_xor(dp,4);
    const float w = expf(dp*scale);          // no max-shift: scores ~N(0,1), safe in fp32
    den += w;
    acc.x += w*v4.x; acc.y += w*v4.y; acc.z += w*v4.z; acc.w += w*v4.w;
  }
  float4 o = {0,0,0,0};
  if (p1 > p0){ const float r = 1.f/den; o.x=acc.x*r; o.y=acc.y*r; o.z=acc.z*r; o.w=acc.w*r; }
  *(float4*)&AGG[((long)dt*NN + d)*256 + lane*4] = o;
}

// ---------------- layernorm (one wave per row of 256) ----------------
__global__ void ln_k(const float* __restrict__ HP, float* __restrict__ H,
                     const float* __restrict__ g, const float* __restrict__ b){
  const int wid = blockIdx.x*4 + (threadIdx.x>>6);  // (t*N+n)
  const int lane = threadIdx.x & 63;
  const int t = wid >> 14;
  const float4 v = *(const float4*)&HP[(long)wid*256 + lane*4];
  float s = v.x+v.y+v.z+v.w;
  #pragma unroll
  for(int o=1;o<64;o<<=1) s += __shfl_xor(s,o);
  const float mu = s*(1.f/256.f);
  const float4 dv = {v.x-mu, v.y-mu, v.z-mu, v.w-mu};
  float sq = dv.x*dv.x + dv.y*dv.y + dv.z*dv.z + dv.w*dv.w;
  #pragma unroll
  for(int o=1;o<64;o<<=1) sq += __shfl_xor(sq,o);
  const float rstd = rsqrtf(sq*(1.f/256.f) + 1e-5f);
  const int c = lane*4;
  const float4 gv = *(const float4*)&g[t*256 + c];
  const float4 bv = *(const float4*)&b[t*256 + c];
  float4 o4 = {dv.x*rstd*gv.x + bv.x, dv.y*rstd*gv.y + bv.y,
               dv.z*rstd*gv.z + bv.z, dv.w*rstd*gv.w + bv.w};
  *(float4*)&H[(long)wid*256 + lane*4] = o4;
}

// ---------------- host ----------------
extern "C" void kernel_launch(void* const* d_in, const int* in_sizes, int n_in,
                              void* d_out, int out_size, void* d_ws, size_t ws_size,
                              hipStream_t stream) {
  const float* node_ft = (const float*)d_in[0];
  const float* scalars = (const float*)d_in[1];
  const int*   src_idx = (const int*)d_in[2];
  const int*   dst_idx = (const int*)d_in[3];
  const float* proj_w  = (const float*)d_in[4];
  const float* proj_b  = (const float*)d_in[5];
  const float* pv_ww   = (const float*)d_in[6];
  const float* pv_wb   = (const float*)d_in[7];
  const float* pv_lw   = (const float*)d_in[8];
  const float* pv_lb   = (const float*)d_in[9];
  const float* pv_sw   = (const float*)d_in[10];
  const float* pv_sb   = (const float*)d_in[11];
  const float* pv_gw   = (const float*)d_in[12];
  const float* pv_gb   = (const float*)d_in[13];
  const float* pv_fcw  = (const float*)d_in[14];
  const float* pv_fcb  = (const float*)d_in[15];
  const float* ima_w1  = (const float*)d_in[16];
  const float* ima_b1  = (const float*)d_in[17];
  const float* ima_w2  = (const float*)d_in[18];
  const float* lyr_k_w = (const float*)d_in[19];
  const float* lyr_q_w = (const float*)d_in[20];
  const float* lyr_v_w = (const float*)d_in[21];
  const float* lyr_fc_w= (const float*)d_in[22];
  const float* lyr_k_b = (const float*)d_in[23];
  const float* lyr_q_b = (const float*)d_in[24];
  const float* lyr_v_b = (const float*)d_in[25];
  const float* lyr_fc_b= (const float*)d_in[26];
  const float* lyr_att_w=(const float*)d_in[27];
  const float* lyr_val_w=(const float*)d_in[28];
  const float* lyr_canon=(const float*)d_in[29];
  const float* lyr_res = (const float*)d_in[30];
  const float* lyr_ln_g= (const float*)d_in[31];
  const float* lyr_ln_b= (const float*)d_in[32];
  const float* out_w   = (const float*)d_in[33];
  const float* out_b   = (const float*)d_in[34];
  const int*   sel     = (const int*)d_in[35];
  float* outp = (float*)d_out;

  char* ws = (char*)d_ws;
  size_t o = 0;
  auto alloc = [&](size_t bytes)->char*{ char* p = ws + o; o = (o + bytes + 255) & ~(size_t)255; return p; };

  int*   cnt    = (int*)  alloc(2*NN*4);
  int*   cur    = (int*)  alloc(2*NN*4);
  int*   offs   = (int*)  alloc(2*(NN+1)*4);
  int*   elist  = (int*)  alloc(2*EE*4);
  u16*   projwt = (u16*)  alloc((size_t)TT*128*256*2);
  u16*   fwt    = (u16*)  alloc((size_t)TT*6*1024*256*2);
  u16*   imaw1t = (u16*)  alloc((size_t)256*128*2);
  u16*   kwt    = (u16*)  alloc((size_t)4*256*256*2);
  u16*   qwt    = (u16*)  alloc((size_t)4*256*256*2);
  u16*   vwt    = (u16*)  alloc((size_t)4*256*256*2);
  u16*   fcwt   = (u16*)  alloc((size_t)4*256*256*2);
  u16*   outwt  = (u16*)  alloc((size_t)64*256*2);
  float* hbuf   = (float*)alloc((size_t)TT*NN*256*4);
  float* wbuf   = (float*)alloc((size_t)TT*NN*7*4);
  char*  arena  = alloc((size_t)176160768);
  if (o > ws_size) return;  // workspace insufficient — fail visibly (poison stays)

  u16*   zbuf = (u16*)arena;                          // (T,N,7,256) bf16, phase A
  u16*   W1   = (u16*)(arena + 117440512);            // (T*N*7,128) bf16, phase A
  float* Qb   = (float*)arena;                        // phase B (z dead)
  float* KEb  = (float*)(arena + 33554432);
  float* VEb  = (float*)(arena + 67108864);
  float* AGG  = (float*)(arena + 100663296);
  float* HP   = (float*)(arena + 134217728);

  // ---- CSR build (per direction e: dst -> list of sources) ----
  hipMemsetAsync(cnt, 0, 2*NN*4, stream);
  hipMemsetAsync(cur, 0, 2*NN*4, stream);
  csr_hist   <<<2*EE/256, 256, 0, stream>>>(dst_idx, cnt);
  csr_scan   <<<2, 256, 0, stream>>>(cnt, offs);
  csr_scatter<<<2*EE/256, 256, 0, stream>>>(dst_idx, src_idx, offs, cur, elist);

  // ---- weights: fp32 -> bf16, transposed to (Nc x K) ----
  tconv<<<dim3( 4,8, 2), dim3(32,8), 0, stream>>>(proj_w,   projwt, 128, 256);
  tconv<<<dim3(32,8,12), dim3(32,8), 0, stream>>>(pv_fcw,   fwt,   1024, 256);
  tconv<<<dim3( 8,4, 1), dim3(32,8), 0, stream>>>(ima_w1,   imaw1t, 256, 128);
  tconv<<<dim3( 8,8, 4), dim3(32,8), 0, stream>>>(lyr_k_w,  kwt,    256, 256);
  tconv<<<dim3( 8,8, 4), dim3(32,8), 0, stream>>>(lyr_q_w,  qwt,    256, 256);
  tconv<<<dim3( 8,8, 4), dim3(32,8), 0, stream>>>(lyr_v_w,  vwt,    256, 256);
  tconv<<<dim3( 8,8, 4), dim3(32,8), 0, stream>>>(lyr_fc_w, fcwt,   256, 256);
  tconv<<<dim3( 8,2, 1), dim3(32,8), 0, stream>>>(out_w,    outwt,  256, 64);

  // ---- h0 = gelu(node_ft @ proj_w + b) -> zbuf slot 0 ----
  gemm_k<64,256,64,1,4,0,1><<<dim3(256,TT), 256, 0, stream>>>(
      node_ft, projwt, proj_b, zbuf, 128, 128, 1792,
      (long)NN*128, 32768L, 256L, (long)NN*1792, nullptr, nullptr, nullptr);

  // ---- posvect -> zbuf slots 1..6 ----
  posvect_k<<<dim3(256,12), 256, 0, stream>>>(scalars, pv_ww, pv_wb, pv_lw, pv_lb,
      pv_sw, pv_sb, pv_gw, pv_gb, fwt, pv_fcb, zbuf);

  // ---- IMA gate: W1 = tanh(z @ ima_w1 + b1); w = W1 @ ima_w2; h = softmax(w).z ----
  gemm_k<64,128,64,2,2,1,2><<<dim3(3584,1), 256, 0, stream>>>(
      zbuf, imaw1t, ima_b1, W1, 256, 256, 128,
      0L, 0L, 0L, 0L, nullptr, nullptr, nullptr);
  ima_dot    <<<TT*NN*7/4, 256, 0, stream>>>(W1, ima_w2, wbuf);
  ima_combine<<<TT*NN/4,   256, 0, stream>>>(zbuf, wbuf, hbuf);

  // ---- layers ----
  for (int l = 0; l < 2; ++l){
    gemm_k<64,256,64,1,4,0,0><<<dim3(256,TT), 256, 0, stream>>>(
        hbuf, qwt + (size_t)l*2*65536, lyr_q_b + l*2*256, Qb, 256, 256, 256,
        (long)NN*256, 65536L, 256L, (long)NN*256, nullptr, nullptr, nullptr);
    gemm_k<64,256,64,1,4,0,0><<<dim3(256,TT), 256, 0, stream>>>(
        hbuf, kwt + (size_t)l*2*65536, lyr_k_b + l*2*256, KEb, 256, 256, 256,
        (long)NN*256, 65536L, 256L, (long)NN*256, nullptr, nullptr, nullptr);
    gemm_k<64,256,64,1,4,0,0><<<dim3(256,TT), 256, 0, stream>>>(
        hbuf, vwt + (size_t)l*2*65536, lyr_v_b + l*2*256, VEb, 256, 256, 256,
        (long)NN*256, 65536L, 256L, (long)NN*256, nullptr, nullptr, nullptr);

    head_transform<<<dim3(NN/32, TT*8), 256, 0, stream>>>(KEb, lyr_att_w, l);
    head_transform<<<dim3(NN/32, TT*8), 256, 0, stream>>>(VEb, lyr_val_w, l);

    // e=0: src type 0 -> dst type 1 ; e=1: src type 1 -> dst type 0
    attn_agg<<<NN/4, 256, 0, stream>>>(Qb, KEb, VEb, AGG, offs, elist,
                                       lyr_canon + (l*2+0)*8, 0, 1);
    attn_agg<<<NN/4, 256, 0, stream>>>(Qb, KEb, VEb, AGG, offs, elist,
                                       lyr_canon + (l*2+1)*8, 1, 0);

    gemm_k<64,256,64,1,4,0,3><<<dim3(256,TT), 256, 0, stream>>>(
        AGG, fcwt + (size_t)l*2*65536, lyr_fc_b + l*2*256, HP, 256, 256, 256,
        (long)NN*256, 65536L, 256L, (long)NN*256, hbuf, lyr_res + l*2, nullptr);

    ln_k<<<TT*NN/4, 256, 0, stream>>>(HP, hbuf, lyr_ln_g + l*2*256, lyr_ln_b + l*2*256);
  }

  // ---- out = h[sel] @ out_w + out_b ----
  gemm_k<256,64,64,4,1,0,0><<<dim3(64,1), 256, 0, stream>>>(
      hbuf, outwt, out_b, outp, 256, 256, 64,
      (long)NN*256, 0L, 0L, 0L, nullptr, nullptr, sel);

  (void)in_sizes; (void)n_in; (void)out_size;
}

// Round 2
// 1219.934 us; speedup vs baseline: 1.2773x; 1.2773x over previous
//
#include <hip/hip_runtime.h>
#include <hip/hip_bf16.h>

typedef unsigned short u16;
typedef unsigned int   u32;
typedef __attribute__((ext_vector_type(8))) short bf16x8;
typedef __attribute__((ext_vector_type(4))) float f32x4;
typedef __attribute__((ext_vector_type(4))) u16   u16x4;

constexpr int TT  = 2;
constexpr int NN  = 16384;
constexpr int EE  = 262144;

__device__ __forceinline__ u16 f2b(float f){
  u32 x = __float_as_uint(f);
  u32 r = (x + 0x7fffu + ((x >> 16) & 1u)) >> 16;
  return (u16)r;
}
__device__ __forceinline__ float b2f(u16 u){ return __uint_as_float(((u32)u) << 16); }

// fast tanh via hw exp: exact at both saturated ends
__device__ __forceinline__ float fast_tanh(float u){
  return 1.f - 2.f*__builtin_amdgcn_rcpf(1.f + __expf(2.f*u));
}
// tanh-approx gelu (max abs dev from exact erf-gelu ~3e-3, well under bf16 budget)
__device__ __forceinline__ float gelu_f(float x){
  float u = 0.7978845608028654f * (x + 0.044715f * x*x*x);
  return 0.5f * x * (1.f + fast_tanh(u));
}

// ---------------- CSR build ----------------
__global__ void csr_hist(const int* __restrict__ dst, int* __restrict__ cnt){
  int id = blockIdx.x*256 + threadIdx.x;           // < 2E
  int e = id >> 18;
  atomicAdd(&cnt[e*NN + dst[id]], 1);
}

__global__ void csr_scan(const int* __restrict__ cnt, int* __restrict__ offs){
  const int e = blockIdx.x, tid = threadIdx.x;     // 2 blocks x 256
  const int CH = NN/256;                           // 64
  const int* c = cnt + e*NN;
  int* of = offs + e*(NN+1);
  const int base = tid*CH;
  int s = 0;
  for(int i=0;i<CH;i++) s += c[base+i];
  __shared__ int sm[256];
  sm[tid] = s; __syncthreads();
  for(int o=1;o<256;o<<=1){
    int v = (tid>=o) ? sm[tid-o] : 0;
    __syncthreads();
    sm[tid] += v;
    __syncthreads();
  }
  int run = sm[tid] - s;                           // exclusive prefix of chunk
  for(int i=0;i<CH;i++){ of[base+i] = run; run += c[base+i]; }
  if(tid==255) of[NN] = run;
}

__global__ void csr_scatter(const int* __restrict__ dst, const int* __restrict__ src,
                            const int* __restrict__ offs, int* __restrict__ cur,
                            int* __restrict__ elist){
  int id = blockIdx.x*256 + threadIdx.x;
  int e = id >> 18;
  int d = dst[id];
  int pos = offs[e*(NN+1)+d] + atomicAdd(&cur[e*NN+d], 1);
  elist[e*EE + pos] = src[id];                     // store SOURCE id directly
}

// ---------------- transpose + bf16 convert (weights) ----------------
// in: (K x Nc) fp32 row-major, out: (Nc x K) bf16 row-major; z batches matrices
__global__ void tconv(const float* __restrict__ in, u16* __restrict__ out, int K, int Nc){
  __shared__ float tile[32][33];
  const long base = (long)blockIdx.z * K * Nc;
  const int k0 = blockIdx.x*32, n0 = blockIdx.y*32;
  const int tx = threadIdx.x, ty = threadIdx.y;    // 32 x 8
  for(int i=0;i<32;i+=8)
    tile[ty+i][tx] = in[base + (long)(k0+ty+i)*Nc + n0+tx];
  __syncthreads();
  for(int i=0;i<32;i+=8)
    out[base + (long)(n0+ty+i)*K + k0+tx] = f2b(tile[tx][ty+i]);
}

// ---------------- generic bf16-MFMA GEMM ----------------
// C = epi(A @ B^T_stored + bias).  Bt is (Nc x K) bf16 (pre-transposed).
// EPI: 0 = fp32 +bias; 1 = gelu->bf16; 2 = tanh->bf16; 3 = residual mix fp32
// ASRC: 0 = fp32 A; 1 = bf16 A
template<int BM,int BN,int BK,int WM,int WN,int ASRC,int EPI>
__global__ void __launch_bounds__(256,2)
gemm_k(const void* __restrict__ Av, const u16* __restrict__ Bt,
       const float* __restrict__ bias, void* __restrict__ Cv,
       int K, int lda, int ldc,
       long strideA, long strideB, long strideBias, long strideC,
       const float* __restrict__ resid, const float* __restrict__ resgate,
       const int* __restrict__ selp)
{
  constexpr int WTM = BM/WM, WTN = BN/WN;
  constexpr int RM = WTM/16, RN = WTN/16;
  constexpr int LA = BK + 8, LB = BK + 8;          // pad: 2-way LDS aliasing only
  __shared__ u16 lA[BM*LA];
  __shared__ u16 lB[BN*LB];

  const int tid = threadIdx.x;
  const int by  = blockIdx.y;
  const int m0  = blockIdx.x * BM;
  const int lane = tid & 63, wvi = tid >> 6;
  const int wr = wvi / WN, wc = wvi % WN;
  const int wr0 = wr * WTM, wc0 = wc * WTN;
  const int l16 = lane & 15, qd = lane >> 4;

  long aoff = (long)by * strideA;
  if (selp) aoff += (long)selp[0] * strideA;
  const float* A32 = (const float*)Av;
  const u16*   A16 = (const u16*)Av;
  const u16*   Bp  = Bt + (long)by * strideB;

  f32x4 acc[RM][RN];
  #pragma unroll
  for(int i=0;i<RM;i++)
    #pragma unroll
    for(int j=0;j<RN;j++) acc[i][j] = (f32x4){0.f,0.f,0.f,0.f};

  for(int k0=0;k0<K;k0+=BK){
    if constexpr (ASRC == 0){
      for(int idx=tid; idx < BM*BK/4; idx += 256){
        int r = idx / (BK/4), c = (idx % (BK/4))*4;
        const float4 v = *(const float4*)(A32 + aoff + (long)(m0+r)*lda + k0 + c);
        u16x4 ov; ov.x=f2b(v.x); ov.y=f2b(v.y); ov.z=f2b(v.z); ov.w=f2b(v.w);
        *(u16x4*)&lA[r*LA + c] = ov;
      }
    } else {
      for(int idx=tid; idx < BM*BK/8; idx += 256){
        int r = idx / (BK/8), c = (idx % (BK/8))*8;
        *(uint4*)&lA[r*LA + c] = *(const uint4*)(A16 + aoff + (long)(m0+r)*lda + k0 + c);
      }
    }
    for(int idx=tid; idx < BN*BK/8; idx += 256){
      int n = idx / (BK/8), c = (idx % (BK/8))*8;
      *(uint4*)&lB[n*LB + c] = *(const uint4*)(Bp + (long)n*K + k0 + c);
    }
    __syncthreads();
    #pragma unroll
    for(int ks=0; ks<BK; ks+=32){
      bf16x8 af[RM], bfr[RN];
      #pragma unroll
      for(int i=0;i<RM;i++) af[i]  = *(const bf16x8*)&lA[(wr0 + i*16 + l16)*LA + ks + qd*8];
      #pragma unroll
      for(int j=0;j<RN;j++) bfr[j] = *(const bf16x8*)&lB[(wc0 + j*16 + l16)*LB + ks + qd*8];
      #pragma unroll
      for(int i=0;i<RM;i++)
        #pragma unroll
        for(int j=0;j<RN;j++)
          acc[i][j] = __builtin_amdgcn_mfma_f32_16x16x32_bf16(af[i], bfr[j], acc[i][j], 0,0,0);
    }
    __syncthreads();
  }

  float alpha = 0.f;
  if constexpr (EPI == 3) alpha = 1.f/(1.f + expf(-resgate[by]));
  #pragma unroll
  for(int i=0;i<RM;i++){
    #pragma unroll
    for(int j=0;j<RN;j++){
      const int col = wc0 + j*16 + l16;
      const float bv = bias[(long)by*strideBias + col];
      #pragma unroll
      for(int r=0;r<4;r++){
        const int row = m0 + wr0 + i*16 + qd*4 + r;
        float v = acc[i][j][r] + bv;
        const long cidx = (long)by*strideC + (long)row*ldc + col;
        if constexpr (EPI == 0) ((float*)Cv)[cidx] = v;
        else if constexpr (EPI == 1) ((u16*)Cv)[cidx] = f2b(gelu_f(v));
        else if constexpr (EPI == 2) ((u16*)Cv)[cidx] = f2b(fast_tanh(v));
        else {
          const float hv = resid[(long)by*strideC + (long)row*ldc + col];
          ((float*)Cv)[cidx] = v*alpha + hv*(1.f - alpha);
        }
      }
    }
  }
}

// ---------------- posvect: A generated from per-row scalar, fused GEMM ----------------
// A-tile (64 rows x 64 j) generated with HW transcendentals; each thread makes
// 8 consecutive j for one row -> one ds_write_b128. Activation class uniform per K-tile.
__global__ void __launch_bounds__(256,2)
posvect_k(const float* __restrict__ scalars,
          const float* __restrict__ ww, const float* __restrict__ wb,
          const float* __restrict__ lw, const float* __restrict__ lb,
          const float* __restrict__ sw, const float* __restrict__ sb,
          const float* __restrict__ gw, const float* __restrict__ gb,
          const u16* __restrict__ fwt, const float* __restrict__ fcb,
          u16* __restrict__ zb)
{
  __shared__ u16 lA[64*72];
  __shared__ u16 lB[256*72];
  __shared__ float xs[64];
  const int tid = threadIdx.x;
  const int by = blockIdx.y;
  const int t = by / 6, m = by % 6;
  const int m0 = blockIdx.x * 64;
  const int lane = tid & 63, wvi = tid >> 6;
  const int wc0 = wvi * 64;
  const int l16 = lane & 15, qd = lane >> 4;
  const int pofs = (t*6 + m) * 256;

  if (tid < 64) xs[tid] = scalars[((long)t*NN + m0 + tid)*6 + m];

  const u16* Bp = fwt + (long)by * (1024*256);

  f32x4 acc[4][4];
  #pragma unroll
  for(int i=0;i<4;i++)
    #pragma unroll
    for(int j=0;j<4;j++) acc[i][j] = (f32x4){0.f,0.f,0.f,0.f};

  __syncthreads();

  for(int k0=0;k0<1024;k0+=64){
    const int ia = k0 >> 8;                        // uniform over the block
    const float* wsel = (ia==0)?ww:(ia==1)?lw:(ia==2)?sw:gw;
    const float* bsel = (ia==0)?wb:(ia==1)?lb:(ia==2)?sb:gb;
    wsel += pofs; bsel += pofs;
    const int kh = k0 & 255;
    #pragma unroll
    for(int g=tid; g<512; g+=256){                 // 64 rows x 8 j-groups
      const int row = g >> 3, jg = g & 7;
      const int hh = kh + jg*8;
      const float x = xs[row];
      const float4 wa = *(const float4*)(wsel + hh);
      const float4 wbv= *(const float4*)(wsel + hh + 4);
      const float4 ba = *(const float4*)(bsel + hh);
      const float4 bbv= *(const float4*)(bsel + hh + 4);
      float y[8];
      y[0]=fmaf(x,wa.x,ba.x);  y[1]=fmaf(x,wa.y,ba.y);
      y[2]=fmaf(x,wa.z,ba.z);  y[3]=fmaf(x,wa.w,ba.w);
      y[4]=fmaf(x,wbv.x,bbv.x); y[5]=fmaf(x,wbv.y,bbv.y);
      y[6]=fmaf(x,wbv.z,bbv.z); y[7]=fmaf(x,wbv.w,bbv.w);
      union { u16 u[8]; uint4 v; } pk;
      if (ia==0){
        #pragma unroll
        for(int i=0;i<8;i++) pk.u[i] = f2b(__sinf(y[i]));
      } else if (ia==1){
        #pragma unroll
        for(int i=0;i<8;i++) pk.u[i] = f2b(y[i]);
      } else if (ia==2){
        #pragma unroll
        for(int i=0;i<8;i++){
          const float a = fabsf(y[i]);
          const float sp = fmaxf(y[i],0.f) + __logf(1.f + __expf(-a));
          pk.u[i] = f2b(sp);
        }
      } else {
        #pragma unroll
        for(int i=0;i<8;i++)
          pk.u[i] = f2b(__builtin_amdgcn_rcpf(1.f + __expf(-y[i])));
      }
      *(uint4*)&lA[row*72 + jg*8] = pk.v;          // 144B row stride: 16B-aligned
    }
    for(int idx=tid; idx<2048; idx+=256){
      int n = idx >> 3, c = (idx & 7)*8;
      *(uint4*)&lB[n*72 + c] = *(const uint4*)(Bp + (long)n*1024 + k0 + c);
    }
    __syncthreads();
    #pragma unroll
    for(int ks=0; ks<64; ks+=32){
      bf16x8 af[4], bfr[4];
      #pragma unroll
      for(int i=0;i<4;i++) af[i]  = *(const bf16x8*)&lA[(i*16 + l16)*72 + ks + qd*8];
      #pragma unroll
      for(int jj=0;jj<4;jj++) bfr[jj] = *(const bf16x8*)&lB[(wc0 + jj*16 + l16)*72 + ks + qd*8];
      #pragma unroll
      for(int i=0;i<4;i++)
        #pragma unroll
        for(int jj=0;jj<4;jj++)
          acc[i][jj] = __builtin_amdgcn_mfma_f32_16x16x32_bf16(af[i], bfr[jj], acc[i][jj], 0,0,0);
    }
    __syncthreads();
  }

  #pragma unroll
  for(int i=0;i<4;i++){
    #pragma unroll
    for(int jj=0;jj<4;jj++){
      const int col = wc0 + jj*16 + l16;
      const float bv = fcb[pofs + col];
      #pragma unroll
      for(int r=0;r<4;r++){
        const int row = m0 + i*16 + qd*4 + r;
        const float v = acc[i][jj][r] + bv;
        zb[((long)t*NN + row)*1792 + (m+1)*256 + col] = f2b(gelu_f(v));
      }
    }
  }
}

// ---------------- IMA: dot with ima_w2, then softmax-combine ----------------
__global__ void ima_dot(const u16* __restrict__ W1, const float* __restrict__ w2,
                        float* __restrict__ wbuf){
  const int row = blockIdx.x*4 + (threadIdx.x>>6);
  const int lane = threadIdx.x & 63;
  const u32 u = *(const u32*)&W1[(long)row*128 + lane*2];
  const float2 wv = *(const float2*)&w2[lane*2];
  float s = b2f((u16)(u & 0xffffu))*wv.x + b2f((u16)(u >> 16))*wv.y;
  #pragma unroll
  for(int o=1;o<64;o<<=1) s += __shfl_xor(s,o);
  if (lane == 0) wbuf[row] = s;
}

__global__ void ima_combine(const u16* __restrict__ zb, const float* __restrict__ wbuf,
                            float* __restrict__ H){
  const int row = blockIdx.x*4 + (threadIdx.x>>6);   // (t*N+n)
  const int lane = threadIdx.x & 63;
  const float* w7 = wbuf + (long)row*7;
  float w[7]; float mx = -1e30f;
  #pragma unroll
  for(int m=0;m<7;m++){ w[m] = w7[m]; mx = fmaxf(mx, w[m]); }
  float sum = 0.f;
  #pragma unroll
  for(int m=0;m<7;m++){ w[m] = __expf(w[m]-mx); sum += w[m]; }
  const float inv = __builtin_amdgcn_rcpf(sum);
  float4 acc = {0,0,0,0};
  #pragma unroll
  for(int m=0;m<7;m++){
    const u16x4 z4 = *(const u16x4*)&zb[((long)row*7 + m)*256 + lane*4];
    const float p = w[m]*inv;
    acc.x += p*b2f(z4.x); acc.y += p*b2f(z4.y); acc.z += p*b2f(z4.z); acc.w += p*b2f(z4.w);
  }
  *(float4*)&H[(long)row*256 + lane*4] = acc;
}

// ---------------- per-head 32x32 transform, in place ----------------
// buf (T,N,256); W = wall[(l*2 + t)*8 + h] (32x32): out_j = sum_i x_i W[i][j]
__global__ void head_transform(float* __restrict__ buf, const float* __restrict__ wall, int l){
  const int th = blockIdx.y;
  const int t = th >> 3, h = th & 7;
  const int n0 = blockIdx.x*32;
  __shared__ float Ws[32][33];
  __shared__ float Xs[32][33];
  const float* W = wall + (((long)(l*2 + t)*8 + h)*1024);
  for(int idx=threadIdx.x; idx<1024; idx+=256) Ws[idx>>5][idx&31] = W[idx];
  for(int idx=threadIdx.x; idx<1024; idx+=256){
    int r = idx>>5, c = idx&31;
    Xs[r][c] = buf[((long)t*NN + n0 + r)*256 + h*32 + c];
  }
  __syncthreads();
  const int r = threadIdx.x>>3, j0 = (threadIdx.x&7)*4;
  float o0=0.f,o1=0.f,o2=0.f,o3=0.f;
  #pragma unroll
  for(int i=0;i<32;i++){
    const float x = Xs[r][i];
    o0 += x*Ws[i][j0]; o1 += x*Ws[i][j0+1]; o2 += x*Ws[i][j0+2]; o3 += x*Ws[i][j0+3];
  }
  float4 ov = {o0,o1,o2,o3};
  *(float4*)&buf[((long)t*NN + n0 + r)*256 + h*32 + j0] = ov;
}

// ---------------- attention aggregation: one wave per destination node ----------------
__global__ void attn_agg(const float* __restrict__ Q, const float* __restrict__ KE,
                         const float* __restrict__ VE, float* __restrict__ AGG,
                         const int* __restrict__ offs, const int* __restrict__ elist,
                         const float* __restrict__ canon, int e, int dt){
  const int d = blockIdx.x*4 + (threadIdx.x>>6);
  const int lane = threadIdx.x & 63;
  const float scale = canon[lane>>3] * 0.17677669529663687f;  // canon[h]/sqrt(32)
  const float4 q4 = *(const float4*)&Q[((long)dt*NN + d)*256 + lane*4];
  const int p0 = offs[e*(NN+1) + d], p1 = offs[e*(NN+1) + d + 1];
  const int* el = elist + (long)e*EE;
  const float* KEb = KE + (long)e*NN*256;
  const float* VEb = VE + (long)e*NN*256;
  float4 acc = {0,0,0,0}; float den = 0.f;
  for(int p=p0;p<p1;++p){
    const int s = el[p];
    const float4 k4 = *(const float4*)&KEb[(long)s*256 + lane*4];
    const float4 v4 = *(const float4*)&VEb[(long)s*256 + lane*4];
    float dp = q4.x*k4.x + q4.y*k4.y + q4.z*k4.z + q4.w*k4.w;
    dp += __shfl_xor(dp,1); dp += __shfl_xor(dp,2); dp += __shfl_xor(dp,4);
    const float w = __expf(dp*scale);        // no max-shift: scores ~N(0,1), safe in fp32
    den += w;
    acc.x += w*v4.x; acc.y += w*v4.y; acc.z += w*v4.z; acc.w += w*v4.w;
  }
  float4 o = {0,0,0,0};
  if (p1 > p0){ const float r = 1.f/den; o.x=acc.x*r; o.y=acc.y*r; o.z=acc.z*r; o.w=acc.w*r; }
  *(float4*)&AGG[((long)dt*NN + d)*256 + lane*4] = o;
}

// ---------------- layernorm (one wave per row of 256) ----------------
__global__ void ln_k(const float* __restrict__ HP, float* __restrict__ H,
                     const float* __restrict__ g, const float* __restrict__ b){
  const int wid = blockIdx.x*4 + (threadIdx.x>>6);  // (t*N+n)
  const int lane = threadIdx.x & 63;
  const int t = wid >> 14;
  const float4 v = *(const float4*)&HP[(long)wid*256 + lane*4];
  float s = v.x+v.y+v.z+v.w;
  #pragma unroll
  for(int o=1;o<64;o<<=1) s += __shfl_xor(s,o);
  const float mu = s*(1.f/256.f);
  const float4 dv = {v.x-mu, v.y-mu, v.z-mu, v.w-mu};
  float sq = dv.x*dv.x + dv.y*dv.y + dv.z*dv.z + dv.w*dv.w;
  #pragma unroll
  for(int o=1;o<64;o<<=1) sq += __shfl_xor(sq,o);
  const float rstd = rsqrtf(sq*(1.f/256.f) + 1e-5f);
  const int c = lane*4;
  const float4 gv = *(const float4*)&g[t*256 + c];
  const float4 bv = *(const float4*)&b[t*256 + c];
  float4 o4 = {dv.x*rstd*gv.x + bv.x, dv.y*rstd*gv.y + bv.y,
               dv.z*rstd*gv.z + bv.z, dv.w*rstd*gv.w + bv.w};
  *(float4*)&H[(long)wid*256 + lane*4] = o4;
}

// ---------------- host ----------------
extern "C" void kernel_launch(void* const* d_in, const int* in_sizes, int n_in,
                              void* d_out, int out_size, void* d_ws, size_t ws_size,
                              hipStream_t stream) {
  const float* node_ft = (const float*)d_in[0];
  const float* scalars = (const float*)d_in[1];
  const int*   src_idx = (const int*)d_in[2];
  const int*   dst_idx = (const int*)d_in[3];
  const float* proj_w  = (const float*)d_in[4];
  const float* proj_b  = (const float*)d_in[5];
  const float* pv_ww   = (const float*)d_in[6];
  const float* pv_wb   = (const float*)d_in[7];
  const float* pv_lw   = (const float*)d_in[8];
  const float* pv_lb   = (const float*)d_in[9];
  const float* pv_sw   = (const float*)d_in[10];
  const float* pv_sb   = (const float*)d_in[11];
  const float* pv_gw   = (const float*)d_in[12];
  const float* pv_gb   = (const float*)d_in[13];
  const float* pv_fcw  = (const float*)d_in[14];
  const float* pv_fcb  = (const float*)d_in[15];
  const float* ima_w1  = (const float*)d_in[16];
  const float* ima_b1  = (const float*)d_in[17];
  const float* ima_w2  = (const float*)d_in[18];
  const float* lyr_k_w = (const float*)d_in[19];
  const float* lyr_q_w = (const float*)d_in[20];
  const float* lyr_v_w = (const float*)d_in[21];
  const float* lyr_fc_w= (const float*)d_in[22];
  const float* lyr_k_b = (const float*)d_in[23];
  const float* lyr_q_b = (const float*)d_in[24];
  const float* lyr_v_b = (const float*)d_in[25];
  const float* lyr_fc_b= (const float*)d_in[26];
  const float* lyr_att_w=(const float*)d_in[27];
  const float* lyr_val_w=(const float*)d_in[28];
  const float* lyr_canon=(const float*)d_in[29];
  const float* lyr_res = (const float*)d_in[30];
  const float* lyr_ln_g= (const float*)d_in[31];
  const float* lyr_ln_b= (const float*)d_in[32];
  const float* out_w   = (const float*)d_in[33];
  const float* out_b   = (const float*)d_in[34];
  const int*   sel     = (const int*)d_in[35];
  float* outp = (float*)d_out;

  char* ws = (char*)d_ws;
  size_t o = 0;
  auto alloc = [&](size_t bytes)->char*{ char* p = ws + o; o = (o + bytes + 255) & ~(size_t)255; return p; };

  int*   cnt    = (int*)  alloc(2*NN*4);
  int*   cur    = (int*)  alloc(2*NN*4);
  int*   offs   = (int*)  alloc(2*(NN+1)*4);
  int*   elist  = (int*)  alloc(2*EE*4);
  u16*   projwt = (u16*)  alloc((size_t)TT*128*256*2);
  u16*   fwt    = (u16*)  alloc((size_t)TT*6*1024*256*2);
  u16*   imaw1t = (u16*)  alloc((size_t)256*128*2);
  u16*   kwt    = (u16*)  alloc((size_t)4*256*256*2);
  u16*   qwt    = (u16*)  alloc((size_t)4*256*256*2);
  u16*   vwt    = (u16*)  alloc((size_t)4*256*256*2);
  u16*   fcwt   = (u16*)  alloc((size_t)4*256*256*2);
  u16*   outwt  = (u16*)  alloc((size_t)64*256*2);
  float* hbuf   = (float*)alloc((size_t)TT*NN*256*4);
  float* wbuf   = (float*)alloc((size_t)TT*NN*7*4);
  char*  arena  = alloc((size_t)176160768);
  if (o > ws_size) return;  // workspace insufficient — fail visibly (poison stays)

  u16*   zbuf = (u16*)arena;                          // (T,N,7,256) bf16, phase A
  u16*   W1   = (u16*)(arena + 117440512);            // (T*N*7,128) bf16, phase A
  float* Qb   = (float*)arena;                        // phase B (z dead)
  float* KEb  = (float*)(arena + 33554432);
  float* VEb  = (float*)(arena + 67108864);
  float* AGG  = (float*)(arena + 100663296);
  float* HP   = (float*)(arena + 134217728);

  // ---- CSR build (per direction e: dst -> list of sources) ----
  hipMemsetAsync(cnt, 0, 2*NN*4, stream);
  hipMemsetAsync(cur, 0, 2*NN*4, stream);
  csr_hist   <<<2*EE/256, 256, 0, stream>>>(dst_idx, cnt);
  csr_scan   <<<2, 256, 0, stream>>>(cnt, offs);
  csr_scatter<<<2*EE/256, 256, 0, stream>>>(dst_idx, src_idx, offs, cur, elist);

  // ---- weights: fp32 -> bf16, transposed to (Nc x K) ----
  tconv<<<dim3( 4,8, 2), dim3(32,8), 0, stream>>>(proj_w,   projwt, 128, 256);
  tconv<<<dim3(32,8,12), dim3(32,8), 0, stream>>>(pv_fcw,   fwt,   1024, 256);
  tconv<<<dim3( 8,4, 1), dim3(32,8), 0, stream>>>(ima_w1,   imaw1t, 256, 128);
  tconv<<<dim3( 8,8, 4), dim3(32,8), 0, stream>>>(lyr_k_w,  kwt,    256, 256);
  tconv<<<dim3( 8,8, 4), dim3(32,8), 0, stream>>>(lyr_q_w,  qwt,    256, 256);
  tconv<<<dim3( 8,8, 4), dim3(32,8), 0, stream>>>(lyr_v_w,  vwt,    256, 256);
  tconv<<<dim3( 8,8, 4), dim3(32,8), 0, stream>>>(lyr_fc_w, fcwt,   256, 256);
  tconv<<<dim3( 8,2, 1), dim3(32,8), 0, stream>>>(out_w,    outwt,  256, 64);

  // ---- h0 = gelu(node_ft @ proj_w + b) -> zbuf slot 0 ----
  gemm_k<64,256,64,1,4,0,1><<<dim3(256,TT), 256, 0, stream>>>(
      node_ft, projwt, proj_b, zbuf, 128, 128, 1792,
      (long)NN*128, 32768L, 256L, (long)NN*1792, nullptr, nullptr, nullptr);

  // ---- posvect -> zbuf slots 1..6 ----
  posvect_k<<<dim3(256,12), 256, 0, stream>>>(scalars, pv_ww, pv_wb, pv_lw, pv_lb,
      pv_sw, pv_sb, pv_gw, pv_gb, fwt, pv_fcb, zbuf);

  // ---- IMA gate: W1 = tanh(z @ ima_w1 + b1); w = W1 @ ima_w2; h = softmax(w).z ----
  gemm_k<64,128,64,2,2,1,2><<<dim3(3584,1), 256, 0, stream>>>(
      zbuf, imaw1t, ima_b1, W1, 256, 256, 128,
      0L, 0L, 0L, 0L, nullptr, nullptr, nullptr);
  ima_dot    <<<TT*NN*7/4, 256, 0, stream>>>(W1, ima_w2, wbuf);
  ima_combine<<<TT*NN/4,   256, 0, stream>>>(zbuf, wbuf, hbuf);

  // ---- layers ----
  for (int l = 0; l < 2; ++l){
    gemm_k<64,256,64,1,4,0,0><<<dim3(256,TT), 256, 0, stream>>>(
        hbuf, qwt + (size_t)l*2*65536, lyr_q_b + l*2*256, Qb, 256, 256, 256,
        (long)NN*256, 65536L, 256L, (long)NN*256, nullptr, nullptr, nullptr);
    gemm_k<64,256,64,1,4,0,0><<<dim3(256,TT), 256, 0, stream>>>(
        hbuf, kwt + (size_t)l*2*65536, lyr_k_b + l*2*256, KEb, 256, 256, 256,
        (long)NN*256, 65536L, 256L, (long)NN*256, nullptr, nullptr, nullptr);
    gemm_k<64,256,64,1,4,0,0><<<dim3(256,TT), 256, 0, stream>>>(
        hbuf, vwt + (size_t)l*2*65536, lyr_v_b + l*2*256, VEb, 256, 256, 256,
        (long)NN*256, 65536L, 256L, (long)NN*256, nullptr, nullptr, nullptr);

    head_transform<<<dim3(NN/32, TT*8), 256, 0, stream>>>(KEb, lyr_att_w, l);
    head_transform<<<dim3(NN/32, TT*8), 256, 0, stream>>>(VEb, lyr_val_w, l);

    // e=0: src type 0 -> dst type 1 ; e=1: src type 1 -> dst type 0
    attn_agg<<<NN/4, 256, 0, stream>>>(Qb, KEb, VEb, AGG, offs, elist,
                                       lyr_canon + (l*2+0)*8, 0, 1);
    attn_agg<<<NN/4, 256, 0, stream>>>(Qb, KEb, VEb, AGG, offs, elist,
                                       lyr_canon + (l*2+1)*8, 1, 0);

    gemm_k<64,256,64,1,4,0,3><<<dim3(256,TT), 256, 0, stream>>>(
        AGG, fcwt + (size_t)l*2*65536, lyr_fc_b + l*2*256, HP, 256, 256, 256,
        (long)NN*256, 65536L, 256L, (long)NN*256, hbuf, lyr_res + l*2, nullptr);

    ln_k<<<TT*NN/4, 256, 0, stream>>>(HP, hbuf, lyr_ln_g + l*2*256, lyr_ln_b + l*2*256);
  }

  // ---- out = h[sel] @ out_w + out_b ----
  gemm_k<256,64,64,4,1,0,0><<<dim3(64,1), 256, 0, stream>>>(
      hbuf, outwt, out_b, outp, 256, 256, 64,
      (long)NN*256, 0L, 0L, 0L, nullptr, nullptr, sel);

  (void)in_sizes; (void)n_in; (void)out_size;
}

// Round 3
// 1092.070 us; speedup vs baseline: 1.4269x; 1.1171x over previous
//
#include <hip/hip_runtime.h>
#include <hip/hip_bf16.h>

typedef unsigned short u16;
typedef unsigned int   u32;
typedef __attribute__((ext_vector_type(8))) short bf16x8;
typedef __attribute__((ext_vector_type(4))) float f32x4;
typedef __attribute__((ext_vector_type(4))) u16   u16x4;

constexpr int TT  = 2;
constexpr int NN  = 16384;
constexpr int EE  = 262144;

__device__ __forceinline__ u16 f2b(float f){
  u32 x = __float_as_uint(f);
  u32 r = (x + 0x7fffu + ((x >> 16) & 1u)) >> 16;
  return (u16)r;
}
__device__ __forceinline__ float b2f(u16 u){ return __uint_as_float(((u32)u) << 16); }

__device__ __forceinline__ float fast_tanh(float u){
  return 1.f - 2.f*__builtin_amdgcn_rcpf(1.f + __expf(2.f*u));
}
__device__ __forceinline__ float gelu_f(float x){
  float u = 0.7978845608028654f * (x + 0.044715f * x*x*x);
  return 0.5f * x * (1.f + fast_tanh(u));
}

// ---------------- CSR build ----------------
__global__ void csr_hist(const int* __restrict__ dst, int* __restrict__ cnt){
  int id = blockIdx.x*256 + threadIdx.x;
  int e = id >> 18;
  atomicAdd(&cnt[e*NN + dst[id]], 1);
}

__global__ void csr_scan(const int* __restrict__ cnt, int* __restrict__ offs){
  const int e = blockIdx.x, tid = threadIdx.x;
  const int CH = NN/256;
  const int* c = cnt + e*NN;
  int* of = offs + e*(NN+1);
  const int base = tid*CH;
  int s = 0;
  for(int i=0;i<CH;i++) s += c[base+i];
  __shared__ int sm[256];
  sm[tid] = s; __syncthreads();
  for(int o=1;o<256;o<<=1){
    int v = (tid>=o) ? sm[tid-o] : 0;
    __syncthreads();
    sm[tid] += v;
    __syncthreads();
  }
  int run = sm[tid] - s;
  for(int i=0;i<CH;i++){ of[base+i] = run; run += c[base+i]; }
  if(tid==255) of[NN] = run;
}

__global__ void csr_scatter(const int* __restrict__ dst, const int* __restrict__ src,
                            const int* __restrict__ offs, int* __restrict__ cur,
                            int* __restrict__ elist){
  int id = blockIdx.x*256 + threadIdx.x;
  int e = id >> 18;
  int d = dst[id];
  int pos = offs[e*(NN+1)+d] + atomicAdd(&cur[e*NN+d], 1);
  elist[e*EE + pos] = src[id];
}

// ---------------- transpose + bf16 convert (weights) ----------------
__global__ void tconv(const float* __restrict__ in, u16* __restrict__ out, int K, int Nc){
  __shared__ float tile[32][33];
  const long base = (long)blockIdx.z * K * Nc;
  const int k0 = blockIdx.x*32, n0 = blockIdx.y*32;
  const int tx = threadIdx.x, ty = threadIdx.y;
  for(int i=0;i<32;i+=8)
    tile[ty+i][tx] = in[base + (long)(k0+ty+i)*Nc + n0+tx];
  __syncthreads();
  for(int i=0;i<32;i+=8)
    out[base + (long)(n0+ty+i)*K + k0+tx] = f2b(tile[tx][ty+i]);
}

// ---------------- rank-1 precompute for the linear posvect block ----------------
// u[by][j] = sum_h lw[by][h]*fw[by][256+h][j] ; v likewise with lb
__global__ void uv_k(const float* __restrict__ lw, const float* __restrict__ lb,
                     const float* __restrict__ fcw,
                     float* __restrict__ ubuf, float* __restrict__ vbuf){
  const int by = blockIdx.x;            // 12
  const int j  = threadIdx.x;           // 256
  const float* fw = fcw + ((long)by*1024 + 256)*256 + j;
  const float* lwp = lw + by*256;
  const float* lbp = lb + by*256;
  float u = 0.f, v = 0.f;
  for(int h=0; h<256; h++){
    const float f = fw[(long)h*256];
    u = fmaf(lwp[h], f, u);
    v = fmaf(lbp[h], f, v);
  }
  ubuf[by*256+j] = u; vbuf[by*256+j] = v;
}

// ---------------- pack qkv biases contiguous [z][t][256] (z: K,Q,V) ----------------
__global__ void pack_qkvb(const float* __restrict__ kb, const float* __restrict__ qb,
                          const float* __restrict__ vb, float* __restrict__ qkvb, int l){
  int i = blockIdx.x*256 + threadIdx.x;     // 1536
  int z = i >> 9, r = i & 511;
  const float* src = (z==0)?kb:(z==1)?qb:vb;
  qkvb[i] = src[l*512 + r];
}

// ---------------- generic bf16-MFMA GEMM ----------------
// EPI: 0 = fp32 +bias; 1 = gelu->bf16; 3 = residual mix fp32;
//      4 = tanh, dot with w2 (passed via `resid`), per-row sum -> ((float*)Cv)[row]
// ASRC: 0 = fp32 A; 1 = bf16 A.  ZQKV: blockIdx.z selects K/Q/V weight+dest.
template<int BM,int BN,int BK,int WM,int WN,int ASRC,int EPI,int ZQKV>
__global__ void __launch_bounds__(256,2)
gemm_k(const void* __restrict__ Av, const u16* __restrict__ Bt,
       const float* __restrict__ bias, void* __restrict__ Cv,
       int K, int lda, int ldc,
       long strideA, long strideB, long strideBias, long strideC,
       const float* __restrict__ resid, const float* __restrict__ resgate,
       const int* __restrict__ selp)
{
  constexpr int WTM = BM/WM, WTN = BN/WN;
  constexpr int RM = WTM/16, RN = WTN/16;
  constexpr int LA = BK + 8, LB = BK + 8;
  __shared__ u16 lA[BM*LA];
  __shared__ u16 lB[BN*LB];

  const int tid = threadIdx.x;
  const int by  = blockIdx.y;
  const int m0  = blockIdx.x * BM;
  const int lane = tid & 63, wvi = tid >> 6;
  const int wr = wvi / WN, wc = wvi % WN;
  const int wr0 = wr * WTM, wc0 = wc * WTN;
  const int l16 = lane & 15, qd = lane >> 4;

  int zq = 0; long coff = 0; int boff = 0;
  if constexpr (ZQKV){
    zq = blockIdx.z;
    coff = (zq==0) ? 8388608L : ((zq==1) ? 0L : 16777216L);  // K->KEb, Q->Qb, V->VEb
    boff = zq*512;
  }

  long aoff = (long)by * strideA;
  if (selp) aoff += (long)selp[0] * strideA;
  const float* A32 = (const float*)Av;
  const u16*   A16 = (const u16*)Av;
  const u16*   Bp  = Bt + (long)by * strideB + (long)zq * 262144;

  f32x4 acc[RM][RN];
  #pragma unroll
  for(int i=0;i<RM;i++)
    #pragma unroll
    for(int j=0;j<RN;j++) acc[i][j] = (f32x4){0.f,0.f,0.f,0.f};

  for(int k0=0;k0<K;k0+=BK){
    if constexpr (ASRC == 0){
      for(int idx=tid; idx < BM*BK/4; idx += 256){
        int r = idx / (BK/4), c = (idx % (BK/4))*4;
        const float4 v = *(const float4*)(A32 + aoff + (long)(m0+r)*lda + k0 + c);
        u16x4 ov; ov.x=f2b(v.x); ov.y=f2b(v.y); ov.z=f2b(v.z); ov.w=f2b(v.w);
        *(u16x4*)&lA[r*LA + c] = ov;
      }
    } else {
      for(int idx=tid; idx < BM*BK/8; idx += 256){
        int r = idx / (BK/8), c = (idx % (BK/8))*8;
        *(uint4*)&lA[r*LA + c] = *(const uint4*)(A16 + aoff + (long)(m0+r)*lda + k0 + c);
      }
    }
    for(int idx=tid; idx < BN*BK/8; idx += 256){
      int n = idx / (BK/8), c = (idx % (BK/8))*8;
      *(uint4*)&lB[n*LB + c] = *(const uint4*)(Bp + (long)n*K + k0 + c);
    }
    __syncthreads();
    #pragma unroll
    for(int ks=0; ks<BK; ks+=32){
      bf16x8 af[RM], bfr[RN];
      #pragma unroll
      for(int i=0;i<RM;i++) af[i]  = *(const bf16x8*)&lA[(wr0 + i*16 + l16)*LA + ks + qd*8];
      #pragma unroll
      for(int j=0;j<RN;j++) bfr[j] = *(const bf16x8*)&lB[(wc0 + j*16 + l16)*LB + ks + qd*8];
      #pragma unroll
      for(int i=0;i<RM;i++)
        #pragma unroll
        for(int j=0;j<RN;j++)
          acc[i][j] = __builtin_amdgcn_mfma_f32_16x16x32_bf16(af[i], bfr[j], acc[i][j], 0,0,0);
    }
    __syncthreads();
  }

  if constexpr (EPI == 4){
    // tanh(acc+bias) dot w2 per row -> Cv[m0+row]
    __shared__ float rsum[WN][BM];
    #pragma unroll
    for(int i=0;i<RM;i++){
      #pragma unroll
      for(int r=0;r<4;r++){
        float part = 0.f;
        #pragma unroll
        for(int jj=0;jj<RN;jj++){
          const int col = wc0 + jj*16 + l16;
          const float v = fast_tanh(acc[i][jj][r] + bias[boff + col]);
          part += v * resid[col];
        }
        part += __shfl_xor(part,1); part += __shfl_xor(part,2);
        part += __shfl_xor(part,4); part += __shfl_xor(part,8);
        if (l16 == 0) rsum[wc][wr0 + i*16 + qd*4 + r] = part;
      }
    }
    __syncthreads();
    if (tid < BM){
      float s = 0.f;
      #pragma unroll
      for(int w=0;w<WN;w++) s += rsum[w][tid];
      ((float*)Cv)[m0 + tid] = s;
    }
    return;
  } else {
    float alpha = 0.f;
    if constexpr (EPI == 3) alpha = 1.f/(1.f + __expf(-resgate[by]));
    #pragma unroll
    for(int i=0;i<RM;i++){
      #pragma unroll
      for(int j=0;j<RN;j++){
        const int col = wc0 + j*16 + l16;
        const float bv = bias[(long)by*strideBias + boff + col];
        #pragma unroll
        for(int r=0;r<4;r++){
          const int row = m0 + wr0 + i*16 + qd*4 + r;
          float v = acc[i][j][r] + bv;
          const long cidx = coff + (long)by*strideC + (long)row*ldc + col;
          if constexpr (EPI == 0) ((float*)Cv)[cidx] = v;
          else if constexpr (EPI == 1) ((u16*)Cv)[cidx] = f2b(gelu_f(v));
          else {
            const float hv = resid[(long)by*strideC + (long)row*ldc + col];
            ((float*)Cv)[cidx] = v*alpha + hv*(1.f - alpha);
          }
        }
      }
    }
  }
}

// ---------------- posvect: K=768 (sin/softplus/sigmoid), rank-1 linear in epilogue ----
__global__ void __launch_bounds__(256,2)
posvect_k(const float* __restrict__ scalars,
          const float* __restrict__ ww, const float* __restrict__ wb,
          const float* __restrict__ sw, const float* __restrict__ sb,
          const float* __restrict__ gw, const float* __restrict__ gb,
          const u16* __restrict__ fwt, const float* __restrict__ fcb,
          const float* __restrict__ ubuf, const float* __restrict__ vbuf,
          u16* __restrict__ zb)
{
  __shared__ u16 lA[128*72];
  __shared__ u16 lB[256*72];
  __shared__ float xs[128];
  const int tid = threadIdx.x;
  const int by = blockIdx.y;
  const int t = by / 6, m = by % 6;
  const int m0 = blockIdx.x * 128;
  const int lane = tid & 63, wvi = tid >> 6;
  const int wc0 = wvi * 64;
  const int l16 = lane & 15, qd = lane >> 4;
  const int pofs = by * 256;

  if (tid < 128) xs[tid] = scalars[((long)t*NN + m0 + tid)*6 + m];

  const u16* Bp = fwt + (long)by * (1024*256);

  f32x4 acc[8][4];
  #pragma unroll
  for(int i=0;i<8;i++)
    #pragma unroll
    for(int j=0;j<4;j++) acc[i][j] = (f32x4){0.f,0.f,0.f,0.f};

  __syncthreads();

  const int jg   = tid & 7;     // j-group (8 consecutive j)
  const int row0 = tid >> 3;    // 0..31

  for(int kt=0; kt<12; kt++){
    const int k0 = kt*64 + (kt>=4 ? 256 : 0);        // skip the linear slab
    const int ia = (kt<4) ? 0 : ((kt<8) ? 2 : 3);
    const int hh = (k0 & 255) + jg*8;
    const float* wsel = ((ia==0)?ww:(ia==2)?sw:gw) + pofs;
    const float* bsel = ((ia==0)?wb:(ia==2)?sb:gb) + pofs;
    const float4 wa  = *(const float4*)(wsel + hh);
    const float4 wv2 = *(const float4*)(wsel + hh + 4);
    const float4 ba  = *(const float4*)(bsel + hh);
    const float4 bv2 = *(const float4*)(bsel + hh + 4);
    #pragma unroll
    for(int it=0; it<4; it++){
      const int row = row0 + it*32;
      const float x = xs[row];
      float y[8];
      y[0]=fmaf(x,wa.x,ba.x);   y[1]=fmaf(x,wa.y,ba.y);
      y[2]=fmaf(x,wa.z,ba.z);   y[3]=fmaf(x,wa.w,ba.w);
      y[4]=fmaf(x,wv2.x,bv2.x); y[5]=fmaf(x,wv2.y,bv2.y);
      y[6]=fmaf(x,wv2.z,bv2.z); y[7]=fmaf(x,wv2.w,bv2.w);
      union { u16 u[8]; uint4 v; } pk;
      if (ia==0){
        #pragma unroll
        for(int i=0;i<8;i++) pk.u[i] = f2b(__sinf(y[i]));
      } else if (ia==2){
        #pragma unroll
        for(int i=0;i<8;i++){
          const float a = fabsf(y[i]);
          pk.u[i] = f2b(fmaxf(y[i],0.f) + __logf(1.f + __expf(-a)));
        }
      } else {
        #pragma unroll
        for(int i=0;i<8;i++)
          pk.u[i] = f2b(__builtin_amdgcn_rcpf(1.f + __expf(-y[i])));
      }
      *(uint4*)&lA[row*72 + jg*8] = pk.v;
    }
    for(int idx=tid; idx<2048; idx+=256){
      int n = idx >> 3, c = (idx & 7)*8;
      *(uint4*)&lB[n*72 + c] = *(const uint4*)(Bp + (long)n*1024 + k0 + c);
    }
    __syncthreads();
    #pragma unroll
    for(int ks=0; ks<64; ks+=32){
      bf16x8 af[8], bfr[4];
      #pragma unroll
      for(int i=0;i<8;i++) af[i]  = *(const bf16x8*)&lA[(i*16 + l16)*72 + ks + qd*8];
      #pragma unroll
      for(int jj=0;jj<4;jj++) bfr[jj] = *(const bf16x8*)&lB[(wc0 + jj*16 + l16)*72 + ks + qd*8];
      #pragma unroll
      for(int i=0;i<8;i++)
        #pragma unroll
        for(int jj=0;jj<4;jj++)
          acc[i][jj] = __builtin_amdgcn_mfma_f32_16x16x32_bf16(af[i], bfr[jj], acc[i][jj], 0,0,0);
    }
    __syncthreads();
  }

  #pragma unroll
  for(int i=0;i<8;i++){
    #pragma unroll
    for(int jj=0;jj<4;jj++){
      const int col = wc0 + jj*16 + l16;
      const float bv = fcb[pofs + col] + vbuf[pofs + col];
      const float uu = ubuf[pofs + col];
      #pragma unroll
      for(int r=0;r<4;r++){
        const int row = i*16 + qd*4 + r;
        const float v = acc[i][jj][r] + bv + xs[row]*uu;
        zb[((long)t*NN + m0 + row)*1792 + (m+1)*256 + col] = f2b(gelu_f(v));
      }
    }
  }
}

// ---------------- IMA combine ----------------
__global__ void ima_combine(const u16* __restrict__ zb, const float* __restrict__ wbuf,
                            float* __restrict__ H){
  const int row = blockIdx.x*4 + (threadIdx.x>>6);
  const int lane = threadIdx.x & 63;
  const float* w7 = wbuf + (long)row*7;
  float w[7]; float mx = -1e30f;
  #pragma unroll
  for(int m=0;m<7;m++){ w[m] = w7[m]; mx = fmaxf(mx, w[m]); }
  float sum = 0.f;
  #pragma unroll
  for(int m=0;m<7;m++){ w[m] = __expf(w[m]-mx); sum += w[m]; }
  const float inv = __builtin_amdgcn_rcpf(sum);
  float4 acc = {0,0,0,0};
  #pragma unroll
  for(int m=0;m<7;m++){
    const u16x4 z4 = *(const u16x4*)&zb[((long)row*7 + m)*256 + lane*4];
    const float p = w[m]*inv;
    acc.x += p*b2f(z4.x); acc.y += p*b2f(z4.y); acc.z += p*b2f(z4.z); acc.w += p*b2f(z4.w);
  }
  *(float4*)&H[(long)row*256 + lane*4] = acc;
}

// ---------------- per-head 32x32 transform, KE+VE in one dispatch ----------------
__global__ void head_transform(float* __restrict__ KE, float* __restrict__ VE,
                               const float* __restrict__ wall_att,
                               const float* __restrict__ wall_val, int l){
  float* buf = blockIdx.z ? VE : KE;
  const float* wall = blockIdx.z ? wall_val : wall_att;
  const int th = blockIdx.y;
  const int t = th >> 3, h = th & 7;
  const int n0 = blockIdx.x*32;
  __shared__ float Ws[32][33];
  __shared__ float Xs[32][33];
  const float* W = wall + (((long)(l*2 + t)*8 + h)*1024);
  for(int idx=threadIdx.x; idx<1024; idx+=256) Ws[idx>>5][idx&31] = W[idx];
  for(int idx=threadIdx.x; idx<1024; idx+=256){
    int r = idx>>5, c = idx&31;
    Xs[r][c] = buf[((long)t*NN + n0 + r)*256 + h*32 + c];
  }
  __syncthreads();
  const int r = threadIdx.x>>3, j0 = (threadIdx.x&7)*4;
  float o0=0.f,o1=0.f,o2=0.f,o3=0.f;
  #pragma unroll
  for(int i=0;i<32;i++){
    const float x = Xs[r][i];
    o0 += x*Ws[i][j0]; o1 += x*Ws[i][j0+1]; o2 += x*Ws[i][j0+2]; o3 += x*Ws[i][j0+3];
  }
  float4 ov = {o0,o1,o2,o3};
  *(float4*)&buf[((long)t*NN + n0 + r)*256 + h*32 + j0] = ov;
}

// ---------------- attention aggregation: both directions, unroll-2 prefetch ------
__global__ void attn_agg(const float* __restrict__ Q, const float* __restrict__ KE,
                         const float* __restrict__ VE, float* __restrict__ AGG,
                         const int* __restrict__ offs, const int* __restrict__ elist,
                         const float* __restrict__ canon){
  const int e = blockIdx.y, dt = 1 - e;
  const int d = blockIdx.x*4 + (threadIdx.x>>6);
  const int lane = threadIdx.x & 63;
  const float scale = canon[e*8 + (lane>>3)] * 0.17677669529663687f;
  const float4 q4 = *(const float4*)&Q[((long)dt*NN + d)*256 + lane*4];
  const int p0 = offs[e*(NN+1) + d], p1 = offs[e*(NN+1) + d + 1];
  const int* el = elist + (long)e*EE;
  const float* KEb = KE + (long)e*NN*256;
  const float* VEb = VE + (long)e*NN*256;
  float4 acc = {0,0,0,0}; float den = 0.f;
  int p = p0;
  for(; p+2 <= p1; p += 2){
    const int s0 = el[p], s1 = el[p+1];
    const float4 ka = *(const float4*)&KEb[(long)s0*256 + lane*4];
    const float4 va = *(const float4*)&VEb[(long)s0*256 + lane*4];
    const float4 kb = *(const float4*)&KEb[(long)s1*256 + lane*4];
    const float4 vb = *(const float4*)&VEb[(long)s1*256 + lane*4];
    float da = q4.x*ka.x + q4.y*ka.y + q4.z*ka.z + q4.w*ka.w;
    float db = q4.x*kb.x + q4.y*kb.y + q4.z*kb.z + q4.w*kb.w;
    da += __shfl_xor(da,1); da += __shfl_xor(da,2); da += __shfl_xor(da,4);
    db += __shfl_xor(db,1); db += __shfl_xor(db,2); db += __shfl_xor(db,4);
    const float wa = __expf(da*scale);
    const float wb_ = __expf(db*scale);
    den += wa + wb_;
    acc.x += wa*va.x + wb_*vb.x; acc.y += wa*va.y + wb_*vb.y;
    acc.z += wa*va.z + wb_*vb.z; acc.w += wa*va.w + wb_*vb.w;
  }
  if (p < p1){
    const int s = el[p];
    const float4 k4 = *(const float4*)&KEb[(long)s*256 + lane*4];
    const float4 v4 = *(const float4*)&VEb[(long)s*256 + lane*4];
    float dp = q4.x*k4.x + q4.y*k4.y + q4.z*k4.z + q4.w*k4.w;
    dp += __shfl_xor(dp,1); dp += __shfl_xor(dp,2); dp += __shfl_xor(dp,4);
    const float w = __expf(dp*scale);
    den += w;
    acc.x += w*v4.x; acc.y += w*v4.y; acc.z += w*v4.z; acc.w += w*v4.w;
  }
  float4 o = {0,0,0,0};
  if (p1 > p0){ const float r = 1.f/den; o.x=acc.x*r; o.y=acc.y*r; o.z=acc.z*r; o.w=acc.w*r; }
  *(float4*)&AGG[((long)dt*NN + d)*256 + lane*4] = o;
}

// ---------------- layernorm ----------------
__global__ void ln_k(const float* __restrict__ HP, float* __restrict__ H,
                     const float* __restrict__ g, const float* __restrict__ b){
  const int wid = blockIdx.x*4 + (threadIdx.x>>6);
  const int lane = threadIdx.x & 63;
  const int t = wid >> 14;
  const float4 v = *(const float4*)&HP[(long)wid*256 + lane*4];
  float s = v.x+v.y+v.z+v.w;
  #pragma unroll
  for(int o=1;o<64;o<<=1) s += __shfl_xor(s,o);
  const float mu = s*(1.f/256.f);
  const float4 dv = {v.x-mu, v.y-mu, v.z-mu, v.w-mu};
  float sq = dv.x*dv.x + dv.y*dv.y + dv.z*dv.z + dv.w*dv.w;
  #pragma unroll
  for(int o=1;o<64;o<<=1) sq += __shfl_xor(sq,o);
  const float rstd = rsqrtf(sq*(1.f/256.f) + 1e-5f);
  const int c = lane*4;
  const float4 gv = *(const float4*)&g[t*256 + c];
  const float4 bv = *(const float4*)&b[t*256 + c];
  float4 o4 = {dv.x*rstd*gv.x + bv.x, dv.y*rstd*gv.y + bv.y,
               dv.z*rstd*gv.z + bv.z, dv.w*rstd*gv.w + bv.w};
  *(float4*)&H[(long)wid*256 + lane*4] = o4;
}

// ---------------- host ----------------
extern "C" void kernel_launch(void* const* d_in, const int* in_sizes, int n_in,
                              void* d_out, int out_size, void* d_ws, size_t ws_size,
                              hipStream_t stream) {
  const float* node_ft = (const float*)d_in[0];
  const float* scalars = (const float*)d_in[1];
  const int*   src_idx = (const int*)d_in[2];
  const int*   dst_idx = (const int*)d_in[3];
  const float* proj_w  = (const float*)d_in[4];
  const float* proj_b  = (const float*)d_in[5];
  const float* pv_ww   = (const float*)d_in[6];
  const float* pv_wb   = (const float*)d_in[7];
  const float* pv_lw   = (const float*)d_in[8];
  const float* pv_lb   = (const float*)d_in[9];
  const float* pv_sw   = (const float*)d_in[10];
  const float* pv_sb   = (const float*)d_in[11];
  const float* pv_gw   = (const float*)d_in[12];
  const float* pv_gb   = (const float*)d_in[13];
  const float* pv_fcw  = (const float*)d_in[14];
  const float* pv_fcb  = (const float*)d_in[15];
  const float* ima_w1  = (const float*)d_in[16];
  const float* ima_b1  = (const float*)d_in[17];
  const float* ima_w2  = (const float*)d_in[18];
  const float* lyr_k_w = (const float*)d_in[19];
  const float* lyr_q_w = (const float*)d_in[20];
  const float* lyr_v_w = (const float*)d_in[21];
  const float* lyr_fc_w= (const float*)d_in[22];
  const float* lyr_k_b = (const float*)d_in[23];
  const float* lyr_q_b = (const float*)d_in[24];
  const float* lyr_v_b = (const float*)d_in[25];
  const float* lyr_fc_b= (const float*)d_in[26];
  const float* lyr_att_w=(const float*)d_in[27];
  const float* lyr_val_w=(const float*)d_in[28];
  const float* lyr_canon=(const float*)d_in[29];
  const float* lyr_res = (const float*)d_in[30];
  const float* lyr_ln_g= (const float*)d_in[31];
  const float* lyr_ln_b= (const float*)d_in[32];
  const float* out_w   = (const float*)d_in[33];
  const float* out_b   = (const float*)d_in[34];
  const int*   sel     = (const int*)d_in[35];
  float* outp = (float*)d_out;

  char* ws = (char*)d_ws;
  size_t o = 0;
  auto alloc = [&](size_t bytes)->char*{ char* p = ws + o; o = (o + bytes + 255) & ~(size_t)255; return p; };

  int*   cnt    = (int*)  alloc(2*NN*4);
  int*   cur    = (int*)  alloc(2*NN*4);
  int*   offs   = (int*)  alloc(2*(NN+1)*4);
  int*   elist  = (int*)  alloc(2*EE*4);
  u16*   projwt = (u16*)  alloc((size_t)TT*128*256*2);
  u16*   fwt    = (u16*)  alloc((size_t)TT*6*1024*256*2);
  u16*   imaw1t = (u16*)  alloc((size_t)256*128*2);
  u16*   kwt    = (u16*)  alloc((size_t)4*256*256*2);   // kwt/qwt/vwt contiguous (z-stride 262144 u16)
  u16*   qwt    = (u16*)  alloc((size_t)4*256*256*2);
  u16*   vwt    = (u16*)  alloc((size_t)4*256*256*2);
  u16*   fcwt   = (u16*)  alloc((size_t)4*256*256*2);
  u16*   outwt  = (u16*)  alloc((size_t)64*256*2);
  float* hbuf   = (float*)alloc((size_t)TT*NN*256*4);
  float* wbuf   = (float*)alloc((size_t)TT*NN*7*4);
  float* ubuf   = (float*)alloc((size_t)12*256*4);
  float* vbuf   = (float*)alloc((size_t)12*256*4);
  float* qkvb   = (float*)alloc((size_t)3*2*256*4);
  char*  arena  = alloc((size_t)176160768);
  if (o > ws_size) return;

  u16*   zbuf = (u16*)arena;                          // (T,N,7,256) bf16, phase A
  float* Qb   = (float*)arena;                        // phase B (z dead)
  float* KEb  = (float*)(arena + 33554432);
  float* VEb  = (float*)(arena + 67108864);
  float* AGG  = (float*)(arena + 100663296);
  float* HP   = (float*)(arena + 134217728);

  // ---- CSR build ----
  hipMemsetAsync(cnt, 0, 2*NN*4, stream);
  hipMemsetAsync(cur, 0, 2*NN*4, stream);
  csr_hist   <<<2*EE/256, 256, 0, stream>>>(dst_idx, cnt);
  csr_scan   <<<2, 256, 0, stream>>>(cnt, offs);
  csr_scatter<<<2*EE/256, 256, 0, stream>>>(dst_idx, src_idx, offs, cur, elist);

  // ---- weights: fp32 -> bf16 transposed; rank-1 precompute ----
  tconv<<<dim3( 4,8, 2), dim3(32,8), 0, stream>>>(proj_w,   projwt, 128, 256);
  tconv<<<dim3(32,8,12), dim3(32,8), 0, stream>>>(pv_fcw,   fwt,   1024, 256);
  tconv<<<dim3( 8,4, 1), dim3(32,8), 0, stream>>>(ima_w1,   imaw1t, 256, 128);
  tconv<<<dim3( 8,8, 4), dim3(32,8), 0, stream>>>(lyr_k_w,  kwt,    256, 256);
  tconv<<<dim3( 8,8, 4), dim3(32,8), 0, stream>>>(lyr_q_w,  qwt,    256, 256);
  tconv<<<dim3( 8,8, 4), dim3(32,8), 0, stream>>>(lyr_v_w,  vwt,    256, 256);
  tconv<<<dim3( 8,8, 4), dim3(32,8), 0, stream>>>(lyr_fc_w, fcwt,   256, 256);
  tconv<<<dim3( 8,2, 1), dim3(32,8), 0, stream>>>(out_w,    outwt,  256, 64);
  uv_k <<<12, 256, 0, stream>>>(pv_lw, pv_lb, pv_fcw, ubuf, vbuf);

  // ---- h0 = gelu(node_ft @ proj_w + b) -> zbuf slot 0 ----
  gemm_k<64,256,64,1,4,0,1,0><<<dim3(256,TT), 256, 0, stream>>>(
      node_ft, projwt, proj_b, zbuf, 128, 128, 1792,
      (long)NN*128, 32768L, 256L, (long)NN*1792, nullptr, nullptr, nullptr);

  // ---- posvect -> zbuf slots 1..6 ----
  posvect_k<<<dim3(128,12), 256, 0, stream>>>(scalars, pv_ww, pv_wb,
      pv_sw, pv_sb, pv_gw, pv_gb, fwt, pv_fcb, ubuf, vbuf, zbuf);

  // ---- IMA gate fused: wbuf[row] = tanh(z@W1+b1) . w2 ; then softmax-combine ----
  gemm_k<64,128,64,2,2,1,4,0><<<dim3(3584,1), 256, 0, stream>>>(
      zbuf, imaw1t, ima_b1, wbuf, 256, 256, 0,
      0L, 0L, 0L, 0L, ima_w2, nullptr, nullptr);
  ima_combine<<<TT*NN/4, 256, 0, stream>>>(zbuf, wbuf, hbuf);

  // ---- layers ----
  for (int l = 0; l < 2; ++l){
    pack_qkvb<<<6, 256, 0, stream>>>(lyr_k_b, lyr_q_b, lyr_v_b, qkvb, l);
    // merged K/Q/V: grid.z selects weight set; dests KEb/Qb/VEb via coff
    gemm_k<64,256,64,1,4,0,0,1><<<dim3(256,TT,3), 256, 0, stream>>>(
        hbuf, kwt + (size_t)l*131072, qkvb, Qb, 256, 256, 256,
        (long)NN*256, 65536L, 256L, (long)NN*256, nullptr, nullptr, nullptr);

    head_transform<<<dim3(NN/32, TT*8, 2), 256, 0, stream>>>(KEb, VEb, lyr_att_w, lyr_val_w, l);

    attn_agg<<<dim3(NN/4, 2), 256, 0, stream>>>(Qb, KEb, VEb, AGG, offs, elist,
                                                lyr_canon + l*2*8);

    gemm_k<64,256,64,1,4,0,3,0><<<dim3(256,TT), 256, 0, stream>>>(
        AGG, fcwt + (size_t)l*2*65536, lyr_fc_b + l*2*256, HP, 256, 256, 256,
        (long)NN*256, 65536L, 256L, (long)NN*256, hbuf, lyr_res + l*2, nullptr);

    ln_k<<<TT*NN/4, 256, 0, stream>>>(HP, hbuf, lyr_ln_g + l*2*256, lyr_ln_b + l*2*256);
  }

  // ---- out = h[sel] @ out_w + out_b ----
  gemm_k<256,64,64,4,1,0,0,0><<<dim3(64,1), 256, 0, stream>>>(
      hbuf, outwt, out_b, outp, 256, 256, 64,
      (long)NN*256, 0L, 0L, 0L, nullptr, nullptr, sel);

  (void)in_sizes; (void)n_in; (void)out_size;
}

// Round 4
// 824.254 us; speedup vs baseline: 1.8905x; 1.3249x over previous
//
#include <hip/hip_runtime.h>
#include <hip/hip_bf16.h>

typedef unsigned short u16;
typedef unsigned int   u32;
typedef __attribute__((ext_vector_type(8))) short bf16x8;
typedef __attribute__((ext_vector_type(4))) float f32x4;
typedef __attribute__((ext_vector_type(4))) u16   u16x4;

constexpr int TT  = 2;
constexpr int NN  = 16384;
constexpr int EE  = 262144;

__device__ __forceinline__ u16 f2b(float f){
  u32 x = __float_as_uint(f);
  u32 r = (x + 0x7fffu + ((x >> 16) & 1u)) >> 16;
  return (u16)r;
}
__device__ __forceinline__ float b2f(u16 u){ return __uint_as_float(((u32)u) << 16); }

__device__ __forceinline__ float fast_tanh(float u){
  return 1.f - 2.f*__builtin_amdgcn_rcpf(1.f + __expf(2.f*u));
}
__device__ __forceinline__ float gelu_f(float x){
  float u = 0.7978845608028654f * (x + 0.044715f * x*x*x);
  return 0.5f * x * (1.f + fast_tanh(u));
}

// ---------------- CSR build ----------------
__global__ void csr_hist(const int* __restrict__ dst, int* __restrict__ cnt){
  int id = blockIdx.x*256 + threadIdx.x;
  int e = id >> 18;
  atomicAdd(&cnt[e*NN + dst[id]], 1);
}

__global__ void csr_scan(const int* __restrict__ cnt, int* __restrict__ offs){
  const int e = blockIdx.x, tid = threadIdx.x;
  const int CH = NN/256;
  const int* c = cnt + e*NN;
  int* of = offs + e*(NN+1);
  const int base = tid*CH;
  int s = 0;
  for(int i=0;i<CH;i++) s += c[base+i];
  __shared__ int sm[256];
  sm[tid] = s; __syncthreads();
  for(int o=1;o<256;o<<=1){
    int v = (tid>=o) ? sm[tid-o] : 0;
    __syncthreads();
    sm[tid] += v;
    __syncthreads();
  }
  int run = sm[tid] - s;
  for(int i=0;i<CH;i++){ of[base+i] = run; run += c[base+i]; }
  if(tid==255) of[NN] = run;
}

__global__ void csr_scatter(const int* __restrict__ dst, const int* __restrict__ src,
                            const int* __restrict__ offs, int* __restrict__ cur,
                            int* __restrict__ elist){
  int id = blockIdx.x*256 + threadIdx.x;
  int e = id >> 18;
  int d = dst[id];
  int pos = offs[e*(NN+1)+d] + atomicAdd(&cur[e*NN+d], 1);
  elist[e*EE + pos] = src[id];
}

// ---------------- transpose + bf16 convert (weights) ----------------
__global__ void tconv(const float* __restrict__ in, u16* __restrict__ out, int K, int Nc){
  __shared__ float tile[32][33];
  const long base = (long)blockIdx.z * K * Nc;
  const int k0 = blockIdx.x*32, n0 = blockIdx.y*32;
  const int tx = threadIdx.x, ty = threadIdx.y;
  for(int i=0;i<32;i+=8)
    tile[ty+i][tx] = in[base + (long)(k0+ty+i)*Nc + n0+tx];
  __syncthreads();
  for(int i=0;i<32;i+=8)
    out[base + (long)(n0+ty+i)*K + k0+tx] = f2b(tile[tx][ty+i]);
}

// ---------------- fold head transforms into K/V weights ----------------
// kw_eff[d][h*32+j] = sum_i kw[d][h*32+i]*att[h][i][j]  (SRC_T[e]==e, so type t uses att[l,t])
// written transposed-bf16 into qkvwt (gemm B layout); bias likewise into qkvb.
__global__ void eff_w(const float* __restrict__ kw, const float* __restrict__ vw,
                      const float* __restrict__ kb, const float* __restrict__ vb,
                      const float* __restrict__ att, const float* __restrict__ val,
                      u16* __restrict__ qkvwt, float* __restrict__ qkvb){
  const int h = blockIdx.x, lt = blockIdx.y, kv = blockIdx.z;   // 8 x 4 x 2
  const int l = lt >> 1;
  const float* W = (kv ? vw : kw) + (long)lt*65536;             // (256 d x 256 col)
  const float* A = (kv ? val : att) + (long)lt*8192 + h*1024;   // 32x32
  const float* B = (kv ? vb : kb) + (long)lt*256 + h*32;
  __shared__ float As[32][33];
  for(int idx=threadIdx.x; idx<1024; idx+=256) As[idx>>5][idx&31] = A[idx];
  __syncthreads();
  const int r = threadIdx.x;                                    // d index
  float x[32];
  const float* wr = W + (long)r*256 + h*32;
  #pragma unroll
  for(int i=0;i<32;i++) x[i] = wr[i];
  u16* outb = qkvwt + (kv ? 524288 : 0) + (long)lt*65536;
  #pragma unroll 4
  for(int j=0;j<32;j++){
    float s = 0.f;
    #pragma unroll
    for(int i=0;i<32;i++) s = fmaf(x[i], As[i][j], s);
    outb[(h*32 + j)*256 + r] = f2b(s);                          // B layout: [col][d]
  }
  if (r < 32){
    float s = 0.f;
    #pragma unroll
    for(int i=0;i<32;i++) s = fmaf(B[i], As[i][r], s);
    // qkvb layout: [l][z][t][256], z: 0=K,1=Q,2=V
    qkvb[l*1536 + (kv ? 1024 : 0) + (lt&1)*256 + h*32 + r] = s;
  }
}

__global__ void pack_qb(const float* __restrict__ qb, float* __restrict__ qkvb){
  int i = blockIdx.x*256 + threadIdx.x;   // 1024 = L*T*256
  int l = i >> 9, r = i & 511;
  qkvb[l*1536 + 512 + r] = qb[l*512 + r];
}

// ---------------- rank-1 precompute for the linear posvect block ----------------
__global__ void uv_k(const float* __restrict__ lw, const float* __restrict__ lb,
                     const float* __restrict__ fcw,
                     float* __restrict__ ubuf, float* __restrict__ vbuf){
  const int by = blockIdx.x;            // 12
  const int j  = threadIdx.x;           // 256
  const float* fw = fcw + ((long)by*1024 + 256)*256 + j;
  const float* lwp = lw + by*256;
  const float* lbp = lb + by*256;
  float u = 0.f, v = 0.f;
  for(int h=0; h<256; h++){
    const float f = fw[(long)h*256];
    u = fmaf(lwp[h], f, u);
    v = fmaf(lbp[h], f, v);
  }
  ubuf[by*256+j] = u; vbuf[by*256+j] = v;
}

// ---------------- generic bf16-MFMA GEMM ----------------
// EPI: 0 = fp32 +bias; 1 = gelu->bf16; 3 = residual mix fp32;
//      4 = tanh, dot w2 (via resid), per-row sum -> ((float*)Cv)[row]
// ASRC: 0 = fp32 A; 1 = bf16 A.  ZQKV: blockIdx.z = {K,Q,V}; K/V -> bf16 KV record, Q -> fp32.
template<int BM,int BN,int BK,int WM,int WN,int ASRC,int EPI,int ZQKV>
__global__ void __launch_bounds__(256,2)
gemm_k(const void* __restrict__ Av, const u16* __restrict__ Bt,
       const float* __restrict__ bias, void* __restrict__ Cv,
       int K, int lda, int ldc,
       long strideA, long strideB, long strideBias, long strideC,
       const float* __restrict__ resid, const float* __restrict__ resgate,
       const int* __restrict__ selp, u16* __restrict__ kvout)
{
  constexpr int WTM = BM/WM, WTN = BN/WN;
  constexpr int RM = WTM/16, RN = WTN/16;
  constexpr int LA = BK + 8, LB = BK + 8;
  __shared__ u16 lA[BM*LA];
  __shared__ u16 lB[BN*LB];

  const int tid = threadIdx.x;
  const int by  = blockIdx.y;
  const int m0  = blockIdx.x * BM;
  const int lane = tid & 63, wvi = tid >> 6;
  const int wr = wvi / WN, wc = wvi % WN;
  const int wr0 = wr * WTM, wc0 = wc * WTN;
  const int l16 = lane & 15, qd = lane >> 4;

  int zq = 0; int boff = 0;
  if constexpr (ZQKV){
    zq = blockIdx.z;
    boff = zq*512;
  }

  long aoff = (long)by * strideA;
  if (selp) aoff += (long)selp[0] * strideA;
  const float* A32 = (const float*)Av;
  const u16*   A16 = (const u16*)Av;
  const u16*   Bp  = Bt + (long)by * strideB + (long)zq * 262144;

  f32x4 acc[RM][RN];
  #pragma unroll
  for(int i=0;i<RM;i++)
    #pragma unroll
    for(int j=0;j<RN;j++) acc[i][j] = (f32x4){0.f,0.f,0.f,0.f};

  for(int k0=0;k0<K;k0+=BK){
    if constexpr (ASRC == 0){
      for(int idx=tid; idx < BM*BK/4; idx += 256){
        int r = idx / (BK/4), c = (idx % (BK/4))*4;
        const float4 v = *(const float4*)(A32 + aoff + (long)(m0+r)*lda + k0 + c);
        u16x4 ov; ov.x=f2b(v.x); ov.y=f2b(v.y); ov.z=f2b(v.z); ov.w=f2b(v.w);
        *(u16x4*)&lA[r*LA + c] = ov;
      }
    } else {
      for(int idx=tid; idx < BM*BK/8; idx += 256){
        int r = idx / (BK/8), c = (idx % (BK/8))*8;
        *(uint4*)&lA[r*LA + c] = *(const uint4*)(A16 + aoff + (long)(m0+r)*lda + k0 + c);
      }
    }
    for(int idx=tid; idx < BN*BK/8; idx += 256){
      int n = idx / (BK/8), c = (idx % (BK/8))*8;
      *(uint4*)&lB[n*LB + c] = *(const uint4*)(Bp + (long)n*K + k0 + c);
    }
    __syncthreads();
    #pragma unroll
    for(int ks=0; ks<BK; ks+=32){
      bf16x8 af[RM], bfr[RN];
      #pragma unroll
      for(int i=0;i<RM;i++) af[i]  = *(const bf16x8*)&lA[(wr0 + i*16 + l16)*LA + ks + qd*8];
      #pragma unroll
      for(int j=0;j<RN;j++) bfr[j] = *(const bf16x8*)&lB[(wc0 + j*16 + l16)*LB + ks + qd*8];
      #pragma unroll
      for(int i=0;i<RM;i++)
        #pragma unroll
        for(int j=0;j<RN;j++)
          acc[i][j] = __builtin_amdgcn_mfma_f32_16x16x32_bf16(af[i], bfr[j], acc[i][j], 0,0,0);
    }
    __syncthreads();
  }

  if constexpr (EPI == 4){
    __shared__ float rsum[WN][BM];
    #pragma unroll
    for(int i=0;i<RM;i++){
      #pragma unroll
      for(int r=0;r<4;r++){
        float part = 0.f;
        #pragma unroll
        for(int jj=0;jj<RN;jj++){
          const int col = wc0 + jj*16 + l16;
          const float v = fast_tanh(acc[i][jj][r] + bias[boff + col]);
          part += v * resid[col];
        }
        part += __shfl_xor(part,1); part += __shfl_xor(part,2);
        part += __shfl_xor(part,4); part += __shfl_xor(part,8);
        if (l16 == 0) rsum[wc][wr0 + i*16 + qd*4 + r] = part;
      }
    }
    __syncthreads();
    if (tid < BM){
      float s = 0.f;
      #pragma unroll
      for(int w=0;w<WN;w++) s += rsum[w][tid];
      ((float*)Cv)[m0 + tid] = s;
    }
    return;
  } else {
    float alpha = 0.f;
    if constexpr (EPI == 3) alpha = 1.f/(1.f + __expf(-resgate[by]));
    #pragma unroll
    for(int i=0;i<RM;i++){
      #pragma unroll
      for(int j=0;j<RN;j++){
        const int col = wc0 + j*16 + l16;
        const float bv = bias[(long)by*strideBias + boff + col];
        #pragma unroll
        for(int r=0;r<4;r++){
          const int row = m0 + wr0 + i*16 + qd*4 + r;
          float v = acc[i][j][r] + bv;
          if constexpr (ZQKV){
            if (zq == 1)
              ((float*)Cv)[(long)by*strideC + (long)row*ldc + col] = v;
            else
              kvout[((long)by*NN + row)*512 + (zq==2 ? 256 : 0) + col] = f2b(v);
          } else {
            const long cidx = (long)by*strideC + (long)row*ldc + col;
            if constexpr (EPI == 0) ((float*)Cv)[cidx] = v;
            else if constexpr (EPI == 1) ((u16*)Cv)[cidx] = f2b(gelu_f(v));
            else {
              const float hv = resid[(long)by*strideC + (long)row*ldc + col];
              ((float*)Cv)[cidx] = v*alpha + hv*(1.f - alpha);
            }
          }
        }
      }
    }
  }
}

// ---------------- posvect: K=768 (sin/softplus/sigmoid), rank-1 linear in epilogue ----
__global__ void __launch_bounds__(256,2)
posvect_k(const float* __restrict__ scalars,
          const float* __restrict__ ww, const float* __restrict__ wb,
          const float* __restrict__ sw, const float* __restrict__ sb,
          const float* __restrict__ gw, const float* __restrict__ gb,
          const u16* __restrict__ fwt, const float* __restrict__ fcb,
          const float* __restrict__ ubuf, const float* __restrict__ vbuf,
          u16* __restrict__ zb)
{
  __shared__ u16 lA[128*72];
  __shared__ u16 lB[256*72];
  __shared__ float xs[128];
  const int tid = threadIdx.x;
  const int by = blockIdx.y;
  const int t = by / 6, m = by % 6;
  const int m0 = blockIdx.x * 128;
  const int lane = tid & 63, wvi = tid >> 6;
  const int wc0 = wvi * 64;
  const int l16 = lane & 15, qd = lane >> 4;
  const int pofs = by * 256;

  if (tid < 128) xs[tid] = scalars[((long)t*NN + m0 + tid)*6 + m];

  const u16* Bp = fwt + (long)by * (1024*256);

  f32x4 acc[8][4];
  #pragma unroll
  for(int i=0;i<8;i++)
    #pragma unroll
    for(int j=0;j<4;j++) acc[i][j] = (f32x4){0.f,0.f,0.f,0.f};

  __syncthreads();

  const int jg   = tid & 7;
  const int row0 = tid >> 3;

  for(int kt=0; kt<12; kt++){
    const int k0 = kt*64 + (kt>=4 ? 256 : 0);        // skip the linear slab
    const int ia = (kt<4) ? 0 : ((kt<8) ? 2 : 3);
    const int hh = (k0 & 255) + jg*8;
    const float* wsel = ((ia==0)?ww:(ia==2)?sw:gw) + pofs;
    const float* bsel = ((ia==0)?wb:(ia==2)?sb:gb) + pofs;
    const float4 wa  = *(const float4*)(wsel + hh);
    const float4 wv2 = *(const float4*)(wsel + hh + 4);
    const float4 ba  = *(const float4*)(bsel + hh);
    const float4 bv2 = *(const float4*)(bsel + hh + 4);
    #pragma unroll
    for(int it=0; it<4; it++){
      const int row = row0 + it*32;
      const float x = xs[row];
      float y[8];
      y[0]=fmaf(x,wa.x,ba.x);   y[1]=fmaf(x,wa.y,ba.y);
      y[2]=fmaf(x,wa.z,ba.z);   y[3]=fmaf(x,wa.w,ba.w);
      y[4]=fmaf(x,wv2.x,bv2.x); y[5]=fmaf(x,wv2.y,bv2.y);
      y[6]=fmaf(x,wv2.z,bv2.z); y[7]=fmaf(x,wv2.w,bv2.w);
      union { u16 u[8]; uint4 v; } pk;
      if (ia==0){
        #pragma unroll
        for(int i=0;i<8;i++) pk.u[i] = f2b(__sinf(y[i]));
      } else if (ia==2){
        #pragma unroll
        for(int i=0;i<8;i++){
          const float a = fabsf(y[i]);
          pk.u[i] = f2b(fmaxf(y[i],0.f) + __logf(1.f + __expf(-a)));
        }
      } else {
        #pragma unroll
        for(int i=0;i<8;i++)
          pk.u[i] = f2b(__builtin_amdgcn_rcpf(1.f + __expf(-y[i])));
      }
      *(uint4*)&lA[row*72 + jg*8] = pk.v;
    }
    for(int idx=tid; idx<2048; idx+=256){
      int n = idx >> 3, c = (idx & 7)*8;
      *(uint4*)&lB[n*72 + c] = *(const uint4*)(Bp + (long)n*1024 + k0 + c);
    }
    __syncthreads();
    #pragma unroll
    for(int ks=0; ks<64; ks+=32){
      bf16x8 af[8], bfr[4];
      #pragma unroll
      for(int i=0;i<8;i++) af[i]  = *(const bf16x8*)&lA[(i*16 + l16)*72 + ks + qd*8];
      #pragma unroll
      for(int jj=0;jj<4;jj++) bfr[jj] = *(const bf16x8*)&lB[(wc0 + jj*16 + l16)*72 + ks + qd*8];
      #pragma unroll
      for(int i=0;i<8;i++)
        #pragma unroll
        for(int jj=0;jj<4;jj++)
          acc[i][jj] = __builtin_amdgcn_mfma_f32_16x16x32_bf16(af[i], bfr[jj], acc[i][jj], 0,0,0);
    }
    __syncthreads();
  }

  #pragma unroll
  for(int i=0;i<8;i++){
    #pragma unroll
    for(int jj=0;jj<4;jj++){
      const int col = wc0 + jj*16 + l16;
      const float bv = fcb[pofs + col] + vbuf[pofs + col];
      const float uu = ubuf[pofs + col];
      #pragma unroll
      for(int r=0;r<4;r++){
        const int row = i*16 + qd*4 + r;
        const float v = acc[i][jj][r] + bv + xs[row]*uu;
        zb[((long)t*NN + m0 + row)*1792 + (m+1)*256 + col] = f2b(gelu_f(v));
      }
    }
  }
}

// ---------------- IMA combine ----------------
__global__ void ima_combine(const u16* __restrict__ zb, const float* __restrict__ wbuf,
                            float* __restrict__ H){
  const int row = blockIdx.x*4 + (threadIdx.x>>6);
  const int lane = threadIdx.x & 63;
  const float* w7 = wbuf + (long)row*7;
  float w[7]; float mx = -1e30f;
  #pragma unroll
  for(int m=0;m<7;m++){ w[m] = w7[m]; mx = fmaxf(mx, w[m]); }
  float sum = 0.f;
  #pragma unroll
  for(int m=0;m<7;m++){ w[m] = __expf(w[m]-mx); sum += w[m]; }
  const float inv = __builtin_amdgcn_rcpf(sum);
  float4 acc = {0,0,0,0};
  #pragma unroll
  for(int m=0;m<7;m++){
    const u16x4 z4 = *(const u16x4*)&zb[((long)row*7 + m)*256 + lane*4];
    const float p = w[m]*inv;
    acc.x += p*b2f(z4.x); acc.y += p*b2f(z4.y); acc.z += p*b2f(z4.z); acc.w += p*b2f(z4.w);
  }
  *(float4*)&H[(long)row*256 + lane*4] = acc;
}

// ---------------- attention aggregation: bf16 KV records, both directions --------
__global__ void attn_agg(const float* __restrict__ Q, const u16* __restrict__ KV,
                         u16* __restrict__ AGG,
                         const int* __restrict__ offs, const int* __restrict__ elist,
                         const float* __restrict__ canon){
  const int e = blockIdx.y, dt = 1 - e;
  const int d = blockIdx.x*4 + (threadIdx.x>>6);
  const int lane = threadIdx.x & 63;
  const float scale = canon[e*8 + (lane>>3)] * 0.17677669529663687f;
  const float4 q4 = *(const float4*)&Q[((long)dt*NN + d)*256 + lane*4];
  const int p0 = offs[e*(NN+1) + d], p1 = offs[e*(NN+1) + d + 1];
  const int* el = elist + (long)e*EE;
  const u16* KVb = KV + (long)e*NN*512;
  float4 acc = {0,0,0,0}; float den = 0.f;
  int p = p0;
  for(; p+2 <= p1; p += 2){
    const long s0 = el[p], s1 = el[p+1];
    const u16x4 ka = *(const u16x4*)&KVb[s0*512 + lane*4];
    const u16x4 va = *(const u16x4*)&KVb[s0*512 + 256 + lane*4];
    const u16x4 kb = *(const u16x4*)&KVb[s1*512 + lane*4];
    const u16x4 vb = *(const u16x4*)&KVb[s1*512 + 256 + lane*4];
    float da = q4.x*b2f(ka.x) + q4.y*b2f(ka.y) + q4.z*b2f(ka.z) + q4.w*b2f(ka.w);
    float db = q4.x*b2f(kb.x) + q4.y*b2f(kb.y) + q4.z*b2f(kb.z) + q4.w*b2f(kb.w);
    da += __shfl_xor(da,1); da += __shfl_xor(da,2); da += __shfl_xor(da,4);
    db += __shfl_xor(db,1); db += __shfl_xor(db,2); db += __shfl_xor(db,4);
    const float wa = __expf(da*scale);
    const float wb_ = __expf(db*scale);
    den += wa + wb_;
    acc.x += wa*b2f(va.x) + wb_*b2f(vb.x); acc.y += wa*b2f(va.y) + wb_*b2f(vb.y);
    acc.z += wa*b2f(va.z) + wb_*b2f(vb.z); acc.w += wa*b2f(va.w) + wb_*b2f(vb.w);
  }
  if (p < p1){
    const long s = el[p];
    const u16x4 k4 = *(const u16x4*)&KVb[s*512 + lane*4];
    const u16x4 v4 = *(const u16x4*)&KVb[s*512 + 256 + lane*4];
    float dp = q4.x*b2f(k4.x) + q4.y*b2f(k4.y) + q4.z*b2f(k4.z) + q4.w*b2f(k4.w);
    dp += __shfl_xor(dp,1); dp += __shfl_xor(dp,2); dp += __shfl_xor(dp,4);
    const float w = __expf(dp*scale);
    den += w;
    acc.x += w*b2f(v4.x); acc.y += w*b2f(v4.y); acc.z += w*b2f(v4.z); acc.w += w*b2f(v4.w);
  }
  u16x4 o = {0,0,0,0};
  if (p1 > p0){
    const float r = 1.f/den;
    o.x = f2b(acc.x*r); o.y = f2b(acc.y*r); o.z = f2b(acc.z*r); o.w = f2b(acc.w*r);
  }
  *(u16x4*)&AGG[((long)dt*NN + d)*256 + lane*4] = o;
}

// ---------------- layernorm ----------------
__global__ void ln_k(const float* __restrict__ HP, float* __restrict__ H,
                     const float* __restrict__ g, const float* __restrict__ b){
  const int wid = blockIdx.x*4 + (threadIdx.x>>6);
  const int lane = threadIdx.x & 63;
  const int t = wid >> 14;
  const float4 v = *(const float4*)&HP[(long)wid*256 + lane*4];
  float s = v.x+v.y+v.z+v.w;
  #pragma unroll
  for(int o=1;o<64;o<<=1) s += __shfl_xor(s,o);
  const float mu = s*(1.f/256.f);
  const float4 dv = {v.x-mu, v.y-mu, v.z-mu, v.w-mu};
  float sq = dv.x*dv.x + dv.y*dv.y + dv.z*dv.z + dv.w*dv.w;
  #pragma unroll
  for(int o=1;o<64;o<<=1) sq += __shfl_xor(sq,o);
  const float rstd = rsqrtf(sq*(1.f/256.f) + 1e-5f);
  const int c = lane*4;
  const float4 gv = *(const float4*)&g[t*256 + c];
  const float4 bv = *(const float4*)&b[t*256 + c];
  float4 o4 = {dv.x*rstd*gv.x + bv.x, dv.y*rstd*gv.y + bv.y,
               dv.z*rstd*gv.z + bv.z, dv.w*rstd*gv.w + bv.w};
  *(float4*)&H[(long)wid*256 + lane*4] = o4;
}

// ---------------- host ----------------
extern "C" void kernel_launch(void* const* d_in, const int* in_sizes, int n_in,
                              void* d_out, int out_size, void* d_ws, size_t ws_size,
                              hipStream_t stream) {
  const float* node_ft = (const float*)d_in[0];
  const float* scalars = (const float*)d_in[1];
  const int*   src_idx = (const int*)d_in[2];
  const int*   dst_idx = (const int*)d_in[3];
  const float* proj_w  = (const float*)d_in[4];
  const float* proj_b  = (const float*)d_in[5];
  const float* pv_ww   = (const float*)d_in[6];
  const float* pv_wb   = (const float*)d_in[7];
  const float* pv_lw   = (const float*)d_in[8];
  const float* pv_lb   = (const float*)d_in[9];
  const float* pv_sw   = (const float*)d_in[10];
  const float* pv_sb   = (const float*)d_in[11];
  const float* pv_gw   = (const float*)d_in[12];
  const float* pv_gb   = (const float*)d_in[13];
  const float* pv_fcw  = (const float*)d_in[14];
  const float* pv_fcb  = (const float*)d_in[15];
  const float* ima_w1  = (const float*)d_in[16];
  const float* ima_b1  = (const float*)d_in[17];
  const float* ima_w2  = (const float*)d_in[18];
  const float* lyr_k_w = (const float*)d_in[19];
  const float* lyr_q_w = (const float*)d_in[20];
  const float* lyr_v_w = (const float*)d_in[21];
  const float* lyr_fc_w= (const float*)d_in[22];
  const float* lyr_k_b = (const float*)d_in[23];
  const float* lyr_q_b = (const float*)d_in[24];
  const float* lyr_v_b = (const float*)d_in[25];
  const float* lyr_fc_b= (const float*)d_in[26];
  const float* lyr_att_w=(const float*)d_in[27];
  const float* lyr_val_w=(const float*)d_in[28];
  const float* lyr_canon=(const float*)d_in[29];
  const float* lyr_res = (const float*)d_in[30];
  const float* lyr_ln_g= (const float*)d_in[31];
  const float* lyr_ln_b= (const float*)d_in[32];
  const float* out_w   = (const float*)d_in[33];
  const float* out_b   = (const float*)d_in[34];
  const int*   sel     = (const int*)d_in[35];
  float* outp = (float*)d_out;

  char* ws = (char*)d_ws;
  size_t o = 0;
  auto alloc = [&](size_t bytes)->char*{ char* p = ws + o; o = (o + bytes + 255) & ~(size_t)255; return p; };

  int*   cnt    = (int*)  alloc(2*NN*4);
  int*   cur    = (int*)  alloc(2*NN*4);
  int*   offs   = (int*)  alloc(2*(NN+1)*4);
  int*   elist  = (int*)  alloc(2*EE*4);
  u16*   projwt = (u16*)  alloc((size_t)TT*128*256*2);
  u16*   fwt    = (u16*)  alloc((size_t)TT*6*1024*256*2);
  u16*   imaw1t = (u16*)  alloc((size_t)256*128*2);
  u16*   qkvwt  = (u16*)  alloc((size_t)3*262144*2);   // [K_eff | Q | V_eff], each (L,T,256,256)
  u16*   fcwt   = (u16*)  alloc((size_t)4*256*256*2);
  u16*   outwt  = (u16*)  alloc((size_t)64*256*2);
  float* hbuf   = (float*)alloc((size_t)TT*NN*256*4);
  float* wbuf   = (float*)alloc((size_t)TT*NN*7*4);
  float* ubuf   = (float*)alloc((size_t)12*256*4);
  float* vbuf   = (float*)alloc((size_t)12*256*4);
  float* qkvb   = (float*)alloc((size_t)TT*3*2*256*4); // [l][z][t][256]
  char*  arena  = alloc((size_t)176160768);
  if (o > ws_size) return;

  u16*   zbuf  = (u16*)arena;                         // (T,N,7,256) bf16, phase A
  float* Qb    = (float*)arena;                       // phase B (zbuf dead after ima_combine)
  u16*   KVb   = (u16*)(arena + 33554432);            // (T,N,512) bf16 interleaved K|V
  u16*   AGG16 = (u16*)(arena + 67108864);            // (T,N,256) bf16
  float* HP    = (float*)(arena + 83886080);          // (T,N,256) fp32

  // ---- CSR build ----
  hipMemsetAsync(cnt, 0, 2*NN*4, stream);
  hipMemsetAsync(cur, 0, 2*NN*4, stream);
  csr_hist   <<<2*EE/256, 256, 0, stream>>>(dst_idx, cnt);
  csr_scan   <<<2, 256, 0, stream>>>(cnt, offs);
  csr_scatter<<<2*EE/256, 256, 0, stream>>>(dst_idx, src_idx, offs, cur, elist);

  // ---- weights prep ----
  tconv<<<dim3( 4,8, 2), dim3(32,8), 0, stream>>>(proj_w,   projwt, 128, 256);
  tconv<<<dim3(32,8,12), dim3(32,8), 0, stream>>>(pv_fcw,   fwt,   1024, 256);
  tconv<<<dim3( 8,4, 1), dim3(32,8), 0, stream>>>(ima_w1,   imaw1t, 256, 128);
  tconv<<<dim3( 8,8, 4), dim3(32,8), 0, stream>>>(lyr_q_w,  qkvwt + 262144, 256, 256);
  tconv<<<dim3( 8,8, 4), dim3(32,8), 0, stream>>>(lyr_fc_w, fcwt,   256, 256);
  tconv<<<dim3( 8,2, 1), dim3(32,8), 0, stream>>>(out_w,    outwt,  256, 64);
  eff_w<<<dim3(8,4,2), 256, 0, stream>>>(lyr_k_w, lyr_v_w, lyr_k_b, lyr_v_b,
                                         lyr_att_w, lyr_val_w, qkvwt, qkvb);
  pack_qb<<<4, 256, 0, stream>>>(lyr_q_b, qkvb);
  uv_k <<<12, 256, 0, stream>>>(pv_lw, pv_lb, pv_fcw, ubuf, vbuf);

  // ---- h0 = gelu(node_ft @ proj_w + b) -> zbuf slot 0 ----
  gemm_k<64,256,64,1,4,0,1,0><<<dim3(256,TT), 256, 0, stream>>>(
      node_ft, projwt, proj_b, zbuf, 128, 128, 1792,
      (long)NN*128, 32768L, 256L, (long)NN*1792, nullptr, nullptr, nullptr, nullptr);

  // ---- posvect -> zbuf slots 1..6 ----
  posvect_k<<<dim3(128,12), 256, 0, stream>>>(scalars, pv_ww, pv_wb,
      pv_sw, pv_sb, pv_gw, pv_gb, fwt, pv_fcb, ubuf, vbuf, zbuf);

  // ---- IMA gate fused epilogue, then softmax-combine ----
  gemm_k<64,128,64,2,2,1,4,0><<<dim3(3584,1), 256, 0, stream>>>(
      zbuf, imaw1t, ima_b1, wbuf, 256, 256, 0,
      0L, 0L, 0L, 0L, ima_w2, nullptr, nullptr, nullptr);
  ima_combine<<<TT*NN/4, 256, 0, stream>>>(zbuf, wbuf, hbuf);

  // ---- layers ----
  for (int l = 0; l < 2; ++l){
    // merged K/Q/V with folded head transforms: z=0 K->KVb[..0..255], z=1 Q->Qb, z=2 V->KVb[..256..511]
    gemm_k<64,256,64,1,4,0,0,1><<<dim3(256,TT,3), 256, 0, stream>>>(
        hbuf, qkvwt + (size_t)l*131072, qkvb + (size_t)l*1536, Qb, 256, 256, 256,
        (long)NN*256, 65536L, 256L, (long)NN*256, nullptr, nullptr, nullptr, KVb);

    attn_agg<<<dim3(NN/4, 2), 256, 0, stream>>>(Qb, KVb, AGG16, offs, elist,
                                                lyr_canon + l*2*8);

    gemm_k<64,256,64,1,4,1,3,0><<<dim3(256,TT), 256, 0, stream>>>(
        AGG16, fcwt + (size_t)l*2*65536, lyr_fc_b + l*2*256, HP, 256, 256, 256,
        (long)NN*256, 65536L, 256L, (long)NN*256, hbuf, lyr_res + l*2, nullptr, nullptr);

    ln_k<<<TT*NN/4, 256, 0, stream>>>(HP, hbuf, lyr_ln_g + l*2*256, lyr_ln_b + l*2*256);
  }

  // ---- out = h[sel] @ out_w + out_b ----
  gemm_k<256,64,64,4,1,0,0,0><<<dim3(64,1), 256, 0, stream>>>(
      hbuf, outwt, out_b, outp, 256, 256, 64,
      (long)NN*256, 0L, 0L, 0L, nullptr, nullptr, sel, nullptr);

  (void)in_sizes; (void)n_in; (void)out_size;
}

// Round 6
// 794.882 us; speedup vs baseline: 1.9603x; 1.0370x over previous
//
#include <hip/hip_runtime.h>
#include <hip/hip_bf16.h>

typedef unsigned short u16;
typedef unsigned int   u32;
typedef __attribute__((ext_vector_type(8))) short bf16x8;
typedef __attribute__((ext_vector_type(4))) float f32x4;
typedef __attribute__((ext_vector_type(4))) u16   u16x4;

constexpr int TT  = 2;
constexpr int NN  = 16384;
constexpr int EE  = 262144;

__device__ __forceinline__ u16 f2b(float f){
  u32 x = __float_as_uint(f);
  u32 r = (x + 0x7fffu + ((x >> 16) & 1u)) >> 16;
  return (u16)r;
}
__device__ __forceinline__ float b2f(u16 u){ return __uint_as_float(((u32)u) << 16); }
__device__ __forceinline__ u32 pack2bf(float a, float b){
  __hip_bfloat162 h = __float22bfloat162_rn(make_float2(a, b));
  union { __hip_bfloat162 h2; u32 u; } cv; cv.h2 = h; return cv.u;
}

__device__ __forceinline__ float fast_tanh(float u){
  return 1.f - 2.f*__builtin_amdgcn_rcpf(1.f + __expf(2.f*u));
}
__device__ __forceinline__ float gelu_f(float x){
  float u = 0.7978845608028654f * (x + 0.044715f * x*x*x);
  return 0.5f * x * (1.f + fast_tanh(u));
}

// ---------------- CSR build ----------------
__global__ void csr_hist(const int* __restrict__ dst, int* __restrict__ cnt){
  int id = blockIdx.x*256 + threadIdx.x;
  int e = id >> 18;
  atomicAdd(&cnt[e*NN + dst[id]], 1);
}

__global__ void csr_scan(const int* __restrict__ cnt, int* __restrict__ offs){
  const int e = blockIdx.x, tid = threadIdx.x;
  const int CH = NN/256;
  const int* c = cnt + e*NN;
  int* of = offs + e*(NN+1);
  const int base = tid*CH;
  int s = 0;
  for(int i=0;i<CH;i++) s += c[base+i];
  __shared__ int sm[256];
  sm[tid] = s; __syncthreads();
  for(int o=1;o<256;o<<=1){
    int v = (tid>=o) ? sm[tid-o] : 0;
    __syncthreads();
    sm[tid] += v;
    __syncthreads();
  }
  int run = sm[tid] - s;
  for(int i=0;i<CH;i++){ of[base+i] = run; run += c[base+i]; }
  if(tid==255) of[NN] = run;
}

__global__ void csr_scatter(const int* __restrict__ dst, const int* __restrict__ src,
                            const int* __restrict__ offs, int* __restrict__ cur,
                            int* __restrict__ elist){
  int id = blockIdx.x*256 + threadIdx.x;
  int e = id >> 18;
  int d = dst[id];
  int pos = offs[e*(NN+1)+d] + atomicAdd(&cur[e*NN+d], 1);
  elist[e*EE + pos] = src[id];
}

// ---------------- transpose + bf16 convert (weights) ----------------
__global__ void tconv(const float* __restrict__ in, u16* __restrict__ out, int K, int Nc){
  __shared__ float tile[32][33];
  const long base = (long)blockIdx.z * K * Nc;
  const int k0 = blockIdx.x*32, n0 = blockIdx.y*32;
  const int tx = threadIdx.x, ty = threadIdx.y;
  for(int i=0;i<32;i+=8)
    tile[ty+i][tx] = in[base + (long)(k0+ty+i)*Nc + n0+tx];
  __syncthreads();
  for(int i=0;i<32;i+=8)
    out[base + (long)(n0+ty+i)*K + k0+tx] = f2b(tile[tx][ty+i]);
}

// ---------------- fold head transforms into K/V weights ----------------
__global__ void eff_w(const float* __restrict__ kw, const float* __restrict__ vw,
                      const float* __restrict__ kb, const float* __restrict__ vb,
                      const float* __restrict__ att, const float* __restrict__ val,
                      u16* __restrict__ qkvwt, float* __restrict__ qkvb){
  const int h = blockIdx.x, lt = blockIdx.y, kv = blockIdx.z;   // 8 x 4 x 2
  const int l = lt >> 1;
  const float* W = (kv ? vw : kw) + (long)lt*65536;
  const float* A = (kv ? val : att) + (long)lt*8192 + h*1024;
  const float* B = (kv ? vb : kb) + (long)lt*256 + h*32;
  __shared__ float As[32][33];
  for(int idx=threadIdx.x; idx<1024; idx+=256) As[idx>>5][idx&31] = A[idx];
  __syncthreads();
  const int r = threadIdx.x;
  float x[32];
  const float* wr = W + (long)r*256 + h*32;
  #pragma unroll
  for(int i=0;i<32;i++) x[i] = wr[i];
  u16* outb = qkvwt + (kv ? 524288 : 0) + (long)lt*65536;
  #pragma unroll 4
  for(int j=0;j<32;j++){
    float s = 0.f;
    #pragma unroll
    for(int i=0;i<32;i++) s = fmaf(x[i], As[i][j], s);
    outb[(h*32 + j)*256 + r] = f2b(s);
  }
  if (r < 32){
    float s = 0.f;
    #pragma unroll
    for(int i=0;i<32;i++) s = fmaf(B[i], As[i][r], s);
    qkvb[l*1536 + (kv ? 1024 : 0) + (lt&1)*256 + h*32 + r] = s;
  }
}

__global__ void pack_qb(const float* __restrict__ qb, float* __restrict__ qkvb){
  int i = blockIdx.x*256 + threadIdx.x;   // 1024 = L*T*256
  int l = i >> 9, r = i & 511;
  qkvb[l*1536 + 512 + r] = qb[l*512 + r];
}

// ---------------- rank-1 precompute for the linear posvect block ----------------
__global__ void uv_k(const float* __restrict__ lw, const float* __restrict__ lb,
                     const float* __restrict__ fcw,
                     float* __restrict__ ubuf, float* __restrict__ vbuf){
  const int by = blockIdx.x;            // 12
  const int j  = threadIdx.x;           // 256
  const float* fw = fcw + ((long)by*1024 + 256)*256 + j;
  const float* lwp = lw + by*256;
  const float* lbp = lb + by*256;
  float u = 0.f, v = 0.f;
  for(int h=0; h<256; h++){
    const float f = fw[(long)h*256];
    u = fmaf(lwp[h], f, u);
    v = fmaf(lbp[h], f, v);
  }
  ubuf[by*256+j] = u; vbuf[by*256+j] = v;
}

// ---------------- generic bf16-MFMA GEMM ----------------
// EPI: 0 = fp32 +bias; 1 = gelu->bf16; 4 = tanh dot w2 row-sum; 5 = residual mix + LayerNorm
// ASRC: 0 = fp32 A; 1 = bf16 A.  ZQKV: blockIdx.z = {K,Q,V}; K/V -> bf16 KV record, Q -> bf16.
// NOTE: Cv/resid intentionally NOT __restrict__ — EPI5 runs in-place on hbuf.
template<int BM,int BN,int BK,int WM,int WN,int ASRC,int EPI,int ZQKV>
__global__ void __launch_bounds__(256,2)
gemm_k(const void* __restrict__ Av, const u16* __restrict__ Bt,
       const float* __restrict__ bias, void* Cv,
       int K, int lda, int ldc,
       long strideA, long strideB, long strideBias, long strideC,
       const float* resid, const float* __restrict__ resgate,
       const int* __restrict__ selp, u16* __restrict__ kvout,
       const float* __restrict__ lng, const float* __restrict__ lnb)
{
  constexpr int WTM = BM/WM, WTN = BN/WN;
  constexpr int RM = WTM/16, RN = WTN/16;
  constexpr int LA = BK + 8, LB = BK + 8;
  __shared__ u16 lA[BM*LA];
  __shared__ u16 lB[BN*LB];

  const int tid = threadIdx.x;
  const int by  = blockIdx.y;
  const int m0  = blockIdx.x * BM;
  const int lane = tid & 63, wvi = tid >> 6;
  const int wr = wvi / WN, wc = wvi % WN;
  const int wr0 = wr * WTM, wc0 = wc * WTN;
  const int l16 = lane & 15, qd = lane >> 4;

  int zq = 0; int boff = 0;
  if constexpr (ZQKV){
    zq = blockIdx.z;
    boff = zq*512;
  }

  long aoff = (long)by * strideA;
  if (selp) aoff += (long)selp[0] * strideA;
  const float* A32 = (const float*)Av;
  const u16*   A16 = (const u16*)Av;
  const u16*   Bp  = Bt + (long)by * strideB + (long)zq * 262144;

  f32x4 acc[RM][RN];
  #pragma unroll
  for(int i=0;i<RM;i++)
    #pragma unroll
    for(int j=0;j<RN;j++) acc[i][j] = (f32x4){0.f,0.f,0.f,0.f};

  for(int k0=0;k0<K;k0+=BK){
    if constexpr (ASRC == 0){
      for(int idx=tid; idx < BM*BK/4; idx += 256){
        int r = idx / (BK/4), c = (idx % (BK/4))*4;
        const float4 v = *(const float4*)(A32 + aoff + (long)(m0+r)*lda + k0 + c);
        uint2 o2; o2.x = pack2bf(v.x, v.y); o2.y = pack2bf(v.z, v.w);
        *(uint2*)&lA[r*LA + c] = o2;
      }
    } else {
      for(int idx=tid; idx < BM*BK/8; idx += 256){
        int r = idx / (BK/8), c = (idx % (BK/8))*8;
        *(uint4*)&lA[r*LA + c] = *(const uint4*)(A16 + aoff + (long)(m0+r)*lda + k0 + c);
      }
    }
    for(int idx=tid; idx < BN*BK/8; idx += 256){
      int n = idx / (BK/8), c = (idx % (BK/8))*8;
      *(uint4*)&lB[n*LB + c] = *(const uint4*)(Bp + (long)n*K + k0 + c);
    }
    __syncthreads();
    #pragma unroll
    for(int ks=0; ks<BK; ks+=32){
      bf16x8 af[RM], bfr[RN];
      #pragma unroll
      for(int i=0;i<RM;i++) af[i]  = *(const bf16x8*)&lA[(wr0 + i*16 + l16)*LA + ks + qd*8];
      #pragma unroll
      for(int j=0;j<RN;j++) bfr[j] = *(const bf16x8*)&lB[(wc0 + j*16 + l16)*LB + ks + qd*8];
      #pragma unroll
      for(int i=0;i<RM;i++)
        #pragma unroll
        for(int j=0;j<RN;j++)
          acc[i][j] = __builtin_amdgcn_mfma_f32_16x16x32_bf16(af[i], bfr[j], acc[i][j], 0,0,0);
    }
    __syncthreads();
  }

  if constexpr (EPI == 4){
    __shared__ float rsum[WN][BM];
    #pragma unroll
    for(int i=0;i<RM;i++){
      #pragma unroll
      for(int r=0;r<4;r++){
        float part = 0.f;
        #pragma unroll
        for(int jj=0;jj<RN;jj++){
          const int col = wc0 + jj*16 + l16;
          const float v = fast_tanh(acc[i][jj][r] + bias[boff + col]);
          part += v * resid[col];
        }
        part += __shfl_xor(part,1); part += __shfl_xor(part,2);
        part += __shfl_xor(part,4); part += __shfl_xor(part,8);
        if (l16 == 0) rsum[wc][wr0 + i*16 + qd*4 + r] = part;
      }
    }
    __syncthreads();
    if (tid < BM){
      float s = 0.f;
      #pragma unroll
      for(int w=0;w<WN;w++) s += rsum[w][tid];
      ((float*)Cv)[m0 + tid] = s;
    }
    return;
  } else if constexpr (EPI == 5){
    // residual mix -> LayerNorm fused; Cv == resid buffer (in-place per-row; barrier-separated)
    __shared__ float red1[WN][BM], red2[WN][BM], muv[BM][2];
    const float alpha = 1.f/(1.f + __expf(-resgate[by]));
    #pragma unroll
    for(int i=0;i<RM;i++){
      #pragma unroll
      for(int r=0;r<4;r++){
        const int rloc = wr0 + i*16 + qd*4 + r;
        const int row = m0 + rloc;
        float s1 = 0.f, s2 = 0.f;
        #pragma unroll
        for(int j=0;j<RN;j++){
          const int col = wc0 + j*16 + l16;
          float v = acc[i][j][r] + bias[(long)by*strideBias + col];
          const float hv = resid[(long)by*strideC + (long)row*ldc + col];
          v = v*alpha + hv*(1.f - alpha);
          acc[i][j][r] = v;
          s1 += v; s2 += v*v;
        }
        s1 += __shfl_xor(s1,1); s1 += __shfl_xor(s1,2); s1 += __shfl_xor(s1,4); s1 += __shfl_xor(s1,8);
        s2 += __shfl_xor(s2,1); s2 += __shfl_xor(s2,2); s2 += __shfl_xor(s2,4); s2 += __shfl_xor(s2,8);
        if (l16 == 0){ red1[wc][rloc] = s1; red2[wc][rloc] = s2; }
      }
    }
    __syncthreads();
    if (tid < BM){
      float s1 = 0.f, s2 = 0.f;
      #pragma unroll
      for(int w=0;w<WN;w++){ s1 += red1[w][tid]; s2 += red2[w][tid]; }
      const float mu = s1*(1.f/256.f);
      const float var = s2*(1.f/256.f) - mu*mu;
      muv[tid][0] = mu; muv[tid][1] = rsqrtf(fmaxf(var, 0.f) + 1e-5f);
    }
    __syncthreads();
    #pragma unroll
    for(int i=0;i<RM;i++){
      #pragma unroll
      for(int r=0;r<4;r++){
        const int rloc = wr0 + i*16 + qd*4 + r;
        const int row = m0 + rloc;
        const float mu = muv[rloc][0], rs = muv[rloc][1];
        #pragma unroll
        for(int j=0;j<RN;j++){
          const int col = wc0 + j*16 + l16;
          const float o = (acc[i][j][r]-mu)*rs*lng[by*256+col] + lnb[by*256+col];
          ((float*)Cv)[(long)by*strideC + (long)row*ldc + col] = o;
        }
      }
    }
    return;
  } else {
    #pragma unroll
    for(int i=0;i<RM;i++){
      #pragma unroll
      for(int j=0;j<RN;j++){
        const int col = wc0 + j*16 + l16;
        const float bv = bias[(long)by*strideBias + boff + col];
        #pragma unroll
        for(int r=0;r<4;r++){
          const int row = m0 + wr0 + i*16 + qd*4 + r;
          float v = acc[i][j][r] + bv;
          if constexpr (ZQKV){
            if (zq == 1)
              ((u16*)Cv)[(long)by*strideC + (long)row*ldc + col] = f2b(v);   // Q bf16
            else
              kvout[((long)by*NN + row)*512 + (zq==2 ? 256 : 0) + col] = f2b(v);
          } else {
            const long cidx = (long)by*strideC + (long)row*ldc + col;
            if constexpr (EPI == 0) ((float*)Cv)[cidx] = v;
            else ((u16*)Cv)[cidx] = f2b(gelu_f(v));
          }
        }
      }
    }
  }
}

// ---------------- posvect: K=768 (sin/softplus/sigmoid), rank-1 linear in epilogue ----
__global__ void __launch_bounds__(256,2)
posvect_k(const float* __restrict__ scalars,
          const float* __restrict__ ww, const float* __restrict__ wb,
          const float* __restrict__ sw, const float* __restrict__ sb,
          const float* __restrict__ gw, const float* __restrict__ gb,
          const u16* __restrict__ fwt, const float* __restrict__ fcb,
          const float* __restrict__ ubuf, const float* __restrict__ vbuf,
          u16* __restrict__ zb)
{
  __shared__ u16 lA[128*72];
  __shared__ u16 lB[256*72];
  __shared__ float xs[128];
  const int tid = threadIdx.x;
  const int by = blockIdx.y;
  const int t = by / 6, m = by % 6;
  const int m0 = blockIdx.x * 128;
  const int lane = tid & 63, wvi = tid >> 6;
  const int wc0 = wvi * 64;
  const int l16 = lane & 15, qd = lane >> 4;
  const int pofs = by * 256;

  if (tid < 128) xs[tid] = scalars[((long)t*NN + m0 + tid)*6 + m];

  const u16* Bp = fwt + (long)by * (1024*256);

  f32x4 acc[8][4];
  #pragma unroll
  for(int i=0;i<8;i++)
    #pragma unroll
    for(int j=0;j<4;j++) acc[i][j] = (f32x4){0.f,0.f,0.f,0.f};

  __syncthreads();

  const int jg   = tid & 7;
  const int row0 = tid >> 3;

  for(int kt=0; kt<12; kt++){
    const int k0 = kt*64 + (kt>=4 ? 256 : 0);        // skip the linear slab
    const int ia = (kt<4) ? 0 : ((kt<8) ? 2 : 3);
    const int hh = (k0 & 255) + jg*8;
    const float* wsel = ((ia==0)?ww:(ia==2)?sw:gw) + pofs;
    const float* bsel = ((ia==0)?wb:(ia==2)?sb:gb) + pofs;
    const float4 wa  = *(const float4*)(wsel + hh);
    const float4 wv2 = *(const float4*)(wsel + hh + 4);
    const float4 ba  = *(const float4*)(bsel + hh);
    const float4 bv2 = *(const float4*)(bsel + hh + 4);
    #pragma unroll
    for(int it=0; it<4; it++){
      const int row = row0 + it*32;
      const float x = xs[row];
      float y[8];
      y[0]=fmaf(x,wa.x,ba.x);   y[1]=fmaf(x,wa.y,ba.y);
      y[2]=fmaf(x,wa.z,ba.z);   y[3]=fmaf(x,wa.w,ba.w);
      y[4]=fmaf(x,wv2.x,bv2.x); y[5]=fmaf(x,wv2.y,bv2.y);
      y[6]=fmaf(x,wv2.z,bv2.z); y[7]=fmaf(x,wv2.w,bv2.w);
      float a[8];
      if (ia==0){
        #pragma unroll
        for(int i=0;i<8;i++) a[i] = __sinf(y[i]);
      } else if (ia==2){
        #pragma unroll
        for(int i=0;i<8;i++){
          const float ab = fabsf(y[i]);
          a[i] = fmaxf(y[i],0.f) + __logf(1.f + __expf(-ab));
        }
      } else {
        #pragma unroll
        for(int i=0;i<8;i++)
          a[i] = __builtin_amdgcn_rcpf(1.f + __expf(-y[i]));
      }
      uint4 pv;
      pv.x = pack2bf(a[0],a[1]); pv.y = pack2bf(a[2],a[3]);
      pv.z = pack2bf(a[4],a[5]); pv.w = pack2bf(a[6],a[7]);
      *(uint4*)&lA[row*72 + jg*8] = pv;
    }
    for(int idx=tid; idx<2048; idx+=256){
      int n = idx >> 3, c = (idx & 7)*8;
      *(uint4*)&lB[n*72 + c] = *(const uint4*)(Bp + (long)n*1024 + k0 + c);
    }
    __syncthreads();
    #pragma unroll
    for(int ks=0; ks<64; ks+=32){
      bf16x8 af[8], bfr[4];
      #pragma unroll
      for(int i=0;i<8;i++) af[i]  = *(const bf16x8*)&lA[(i*16 + l16)*72 + ks + qd*8];
      #pragma unroll
      for(int jj=0;jj<4;jj++) bfr[jj] = *(const bf16x8*)&lB[(wc0 + jj*16 + l16)*72 + ks + qd*8];
      #pragma unroll
      for(int i=0;i<8;i++)
        #pragma unroll
        for(int jj=0;jj<4;jj++)
          acc[i][jj] = __builtin_amdgcn_mfma_f32_16x16x32_bf16(af[i], bfr[jj], acc[i][jj], 0,0,0);
    }
    __syncthreads();
  }

  #pragma unroll
  for(int i=0;i<8;i++){
    #pragma unroll
    for(int jj=0;jj<4;jj++){
      const int col = wc0 + jj*16 + l16;
      const float bv = fcb[pofs + col] + vbuf[pofs + col];
      const float uu = ubuf[pofs + col];
      #pragma unroll
      for(int r=0;r<4;r++){
        const int row = i*16 + qd*4 + r;
        const float v = acc[i][jj][r] + bv + xs[row]*uu;
        zb[((long)t*NN + m0 + row)*1792 + (m+1)*256 + col] = f2b(gelu_f(v));
      }
    }
  }
}

// ---------------- IMA combine ----------------
__global__ void ima_combine(const u16* __restrict__ zb, const float* __restrict__ wbuf,
                            float* __restrict__ H){
  const int row = blockIdx.x*4 + (threadIdx.x>>6);
  const int lane = threadIdx.x & 63;
  const float* w7 = wbuf + (long)row*7;
  float w[7]; float mx = -1e30f;
  #pragma unroll
  for(int m=0;m<7;m++){ w[m] = w7[m]; mx = fmaxf(mx, w[m]); }
  float sum = 0.f;
  #pragma unroll
  for(int m=0;m<7;m++){ w[m] = __expf(w[m]-mx); sum += w[m]; }
  const float inv = __builtin_amdgcn_rcpf(sum);
  float4 acc = {0,0,0,0};
  #pragma unroll
  for(int m=0;m<7;m++){
    const u16x4 z4 = *(const u16x4*)&zb[((long)row*7 + m)*256 + lane*4];
    const float p = w[m]*inv;
    acc.x += p*b2f(z4.x); acc.y += p*b2f(z4.y); acc.z += p*b2f(z4.z); acc.w += p*b2f(z4.w);
  }
  *(float4*)&H[(long)row*256 + lane*4] = acc;
}

// ---------------- attention aggregation: split-lane KV gather, unroll-4 ----------
// lanes 0-31: K dims half*8..+7 (head = half>>2); lanes 32-63: V dims half*8..+7.
__global__ void attn_agg(const u16* __restrict__ Q16, const u16* __restrict__ KV,
                         u16* __restrict__ AGG,
                         const int* __restrict__ offs, const int* __restrict__ elist,
                         const float* __restrict__ canon){
  const int e = blockIdx.y, dt = 1 - e;
  const int d = blockIdx.x*4 + (threadIdx.x>>6);
  const int lane = threadIdx.x & 63;
  const int half = lane & 31;
  const float scale = canon[e*8 + (half>>2)] * 0.17677669529663687f;

  const uint4 qv = *(const uint4*)&Q16[((long)dt*NN + d)*256 + half*8];
  float q[8];
  q[0]=b2f((u16)(qv.x&0xffff)); q[1]=b2f((u16)(qv.x>>16));
  q[2]=b2f((u16)(qv.y&0xffff)); q[3]=b2f((u16)(qv.y>>16));
  q[4]=b2f((u16)(qv.z&0xffff)); q[5]=b2f((u16)(qv.z>>16));
  q[6]=b2f((u16)(qv.w&0xffff)); q[7]=b2f((u16)(qv.w>>16));

  const int p0 = offs[e*(NN+1) + d], p1 = offs[e*(NN+1) + d + 1];
  const int* el = elist + (long)e*EE;
  const u16* KVb = KV + (long)e*NN*512;

  float acc[8] = {0,0,0,0,0,0,0,0};
  float den = 0.f;

  auto process = [&](const uint4 kv){
    float f[8];
    f[0]=b2f((u16)(kv.x&0xffff)); f[1]=b2f((u16)(kv.x>>16));
    f[2]=b2f((u16)(kv.y&0xffff)); f[3]=b2f((u16)(kv.y>>16));
    f[4]=b2f((u16)(kv.z&0xffff)); f[5]=b2f((u16)(kv.z>>16));
    f[6]=b2f((u16)(kv.w&0xffff)); f[7]=b2f((u16)(kv.w>>16));
    float dp = q[0]*f[0]+q[1]*f[1]+q[2]*f[2]+q[3]*f[3]
             + q[4]*f[4]+q[5]*f[5]+q[6]*f[6]+q[7]*f[7];
    dp += __shfl_xor(dp,1); dp += __shfl_xor(dp,2);
    const float w = __expf(dp*scale);        // valid in lanes 0-31
    const float wv = __shfl(w, half);        // whole wave active: broadcast K-lane weight
    den += w;
    #pragma unroll
    for(int j=0;j<8;j++) acc[j] += wv*f[j];  // meaningful in lanes 32-63
  };

  int p = p0;
  for(; p+4 <= p1; p += 4){
    const int s0=el[p], s1=el[p+1], s2=el[p+2], s3=el[p+3];
    const uint4 a = *(const uint4*)&KVb[(long)s0*512 + lane*8];
    const uint4 b = *(const uint4*)&KVb[(long)s1*512 + lane*8];
    const uint4 c = *(const uint4*)&KVb[(long)s2*512 + lane*8];
    const uint4 dd= *(const uint4*)&KVb[(long)s3*512 + lane*8];
    process(a); process(b); process(c); process(dd);
  }
  for(; p<p1; ++p){
    const uint4 a = *(const uint4*)&KVb[(long)el[p]*512 + lane*8];
    process(a);
  }

  // Broadcast denominator to V lanes while ALL lanes are active.
  // (ds_bpermute from an EXEC-masked-off lane returns undefined data — doing
  //  this inside `if (lane>=32)` was the round-5 NaN.)
  const float denv = __shfl(den, half);

  if (lane >= 32){
    uint4 o = {0,0,0,0};
    if (p1 > p0){
      const float rden = 1.f/denv;
      o.x = pack2bf(acc[0]*rden, acc[1]*rden);
      o.y = pack2bf(acc[2]*rden, acc[3]*rden);
      o.z = pack2bf(acc[4]*rden, acc[5]*rden);
      o.w = pack2bf(acc[6]*rden, acc[7]*rden);
    }
    *(uint4*)&AGG[((long)dt*NN + d)*256 + half*8] = o;
  }
}

// ---------------- host ----------------
extern "C" void kernel_launch(void* const* d_in, const int* in_sizes, int n_in,
                              void* d_out, int out_size, void* d_ws, size_t ws_size,
                              hipStream_t stream) {
  const float* node_ft = (const float*)d_in[0];
  const float* scalars = (const float*)d_in[1];
  const int*   src_idx = (const int*)d_in[2];
  const int*   dst_idx = (const int*)d_in[3];
  const float* proj_w  = (const float*)d_in[4];
  const float* proj_b  = (const float*)d_in[5];
  const float* pv_ww   = (const float*)d_in[6];
  const float* pv_wb   = (const float*)d_in[7];
  const float* pv_lw   = (const float*)d_in[8];
  const float* pv_lb   = (const float*)d_in[9];
  const float* pv_sw   = (const float*)d_in[10];
  const float* pv_sb   = (const float*)d_in[11];
  const float* pv_gw   = (const float*)d_in[12];
  const float* pv_gb   = (const float*)d_in[13];
  const float* pv_fcw  = (const float*)d_in[14];
  const float* pv_fcb  = (const float*)d_in[15];
  const float* ima_w1  = (const float*)d_in[16];
  const float* ima_b1  = (const float*)d_in[17];
  const float* ima_w2  = (const float*)d_in[18];
  const float* lyr_k_w = (const float*)d_in[19];
  const float* lyr_q_w = (const float*)d_in[20];
  const float* lyr_v_w = (const float*)d_in[21];
  const float* lyr_fc_w= (const float*)d_in[22];
  const float* lyr_k_b = (const float*)d_in[23];
  const float* lyr_q_b = (const float*)d_in[24];
  const float* lyr_v_b = (const float*)d_in[25];
  const float* lyr_fc_b= (const float*)d_in[26];
  const float* lyr_att_w=(const float*)d_in[27];
  const float* lyr_val_w=(const float*)d_in[28];
  const float* lyr_canon=(const float*)d_in[29];
  const float* lyr_res = (const float*)d_in[30];
  const float* lyr_ln_g= (const float*)d_in[31];
  const float* lyr_ln_b= (const float*)d_in[32];
  const float* out_w   = (const float*)d_in[33];
  const float* out_b   = (const float*)d_in[34];
  const int*   sel     = (const int*)d_in[35];
  float* outp = (float*)d_out;

  char* ws = (char*)d_ws;
  size_t o = 0;
  auto alloc = [&](size_t bytes)->char*{ char* p = ws + o; o = (o + bytes + 255) & ~(size_t)255; return p; };

  int*   cnt    = (int*)  alloc(2*NN*4);
  int*   cur    = (int*)  alloc(2*NN*4);
  int*   offs   = (int*)  alloc(2*(NN+1)*4);
  int*   elist  = (int*)  alloc(2*EE*4);
  u16*   projwt = (u16*)  alloc((size_t)TT*128*256*2);
  u16*   fwt    = (u16*)  alloc((size_t)TT*6*1024*256*2);
  u16*   imaw1t = (u16*)  alloc((size_t)256*128*2);
  u16*   qkvwt  = (u16*)  alloc((size_t)3*262144*2);   // [K_eff | Q | V_eff]
  u16*   fcwt   = (u16*)  alloc((size_t)4*256*256*2);
  u16*   outwt  = (u16*)  alloc((size_t)64*256*2);
  float* hbuf   = (float*)alloc((size_t)TT*NN*256*4);
  float* wbuf   = (float*)alloc((size_t)TT*NN*7*4);
  float* ubuf   = (float*)alloc((size_t)12*256*4);
  float* vbuf   = (float*)alloc((size_t)12*256*4);
  float* qkvb   = (float*)alloc((size_t)TT*3*2*256*4); // [l][z][t][256]
  char*  arena  = alloc((size_t)176160768);
  if (o > ws_size) return;

  u16*   zbuf  = (u16*)arena;                         // (T,N,7,256) bf16, phase A
  u16*   Qb16  = (u16*)arena;                         // phase B (zbuf dead after ima_combine)
  u16*   KVb   = (u16*)(arena + 16777216);            // (T,N,512) bf16 interleaved K|V
  u16*   AGG16 = (u16*)(arena + 50331648);            // (T,N,256) bf16

  // ---- CSR build ----
  hipMemsetAsync(cnt, 0, 2*NN*4, stream);
  hipMemsetAsync(cur, 0, 2*NN*4, stream);
  csr_hist   <<<2*EE/256, 256, 0, stream>>>(dst_idx, cnt);
  csr_scan   <<<2, 256, 0, stream>>>(cnt, offs);
  csr_scatter<<<2*EE/256, 256, 0, stream>>>(dst_idx, src_idx, offs, cur, elist);

  // ---- weights prep ----
  tconv<<<dim3( 4,8, 2), dim3(32,8), 0, stream>>>(proj_w,   projwt, 128, 256);
  tconv<<<dim3(32,8,12), dim3(32,8), 0, stream>>>(pv_fcw,   fwt,   1024, 256);
  tconv<<<dim3( 8,4, 1), dim3(32,8), 0, stream>>>(ima_w1,   imaw1t, 256, 128);
  tconv<<<dim3( 8,8, 4), dim3(32,8), 0, stream>>>(lyr_q_w,  qkvwt + 262144, 256, 256);
  tconv<<<dim3( 8,8, 4), dim3(32,8), 0, stream>>>(lyr_fc_w, fcwt,   256, 256);
  tconv<<<dim3( 8,2, 1), dim3(32,8), 0, stream>>>(out_w,    outwt,  256, 64);
  eff_w<<<dim3(8,4,2), 256, 0, stream>>>(lyr_k_w, lyr_v_w, lyr_k_b, lyr_v_b,
                                         lyr_att_w, lyr_val_w, qkvwt, qkvb);
  pack_qb<<<4, 256, 0, stream>>>(lyr_q_b, qkvb);
  uv_k <<<12, 256, 0, stream>>>(pv_lw, pv_lb, pv_fcw, ubuf, vbuf);

  // ---- h0 = gelu(node_ft @ proj_w + b) -> zbuf slot 0 ----
  gemm_k<64,256,64,1,4,0,1,0><<<dim3(256,TT), 256, 0, stream>>>(
      node_ft, projwt, proj_b, zbuf, 128, 128, 1792,
      (long)NN*128, 32768L, 256L, (long)NN*1792, nullptr, nullptr, nullptr, nullptr,
      nullptr, nullptr);

  // ---- posvect -> zbuf slots 1..6 ----
  posvect_k<<<dim3(128,12), 256, 0, stream>>>(scalars, pv_ww, pv_wb,
      pv_sw, pv_sb, pv_gw, pv_gb, fwt, pv_fcb, ubuf, vbuf, zbuf);

  // ---- IMA gate fused epilogue, then softmax-combine ----
  gemm_k<64,128,64,2,2,1,4,0><<<dim3(3584,1), 256, 0, stream>>>(
      zbuf, imaw1t, ima_b1, wbuf, 256, 256, 0,
      0L, 0L, 0L, 0L, ima_w2, nullptr, nullptr, nullptr, nullptr, nullptr);
  ima_combine<<<TT*NN/4, 256, 0, stream>>>(zbuf, wbuf, hbuf);

  // ---- layers ----
  for (int l = 0; l < 2; ++l){
    // merged K/Q/V with folded head transforms: z=0 K->KVb[..0..255], z=1 Q->Qb16, z=2 V->KVb[..256..511]
    gemm_k<64,256,64,1,4,0,0,1><<<dim3(256,TT,3), 256, 0, stream>>>(
        hbuf, qkvwt + (size_t)l*131072, qkvb + (size_t)l*1536, Qb16, 256, 256, 256,
        (long)NN*256, 65536L, 256L, (long)NN*256, nullptr, nullptr, nullptr, KVb,
        nullptr, nullptr);

    attn_agg<<<dim3(NN/4, 2), 256, 0, stream>>>(Qb16, KVb, AGG16, offs, elist,
                                                lyr_canon + l*2*8);

    // fc + residual mix + LayerNorm fused, in-place on hbuf
    gemm_k<64,256,64,1,4,1,5,0><<<dim3(256,TT), 256, 0, stream>>>(
        AGG16, fcwt + (size_t)l*2*65536, lyr_fc_b + l*2*256, hbuf, 256, 256, 256,
        (long)NN*256, 65536L, 256L, (long)NN*256, hbuf, lyr_res + l*2, nullptr, nullptr,
        lyr_ln_g + l*2*256, lyr_ln_b + l*2*256);
  }

  // ---- out = h[sel] @ out_w + out_b ----
  gemm_k<256,64,64,4,1,0,0,0><<<dim3(64,1), 256, 0, stream>>>(
      hbuf, outwt, out_b, outp, 256, 256, 64,
      (long)NN*256, 0L, 0L, 0L, nullptr, nullptr, sel, nullptr, nullptr, nullptr);

  (void)in_sizes; (void)n_in; (void)out_size;
}